// Round 12
// baseline (1461.710 us; speedup 1.0000x reference)
//
#include <hip/hip_runtime.h>
#include <hip/hip_bf16.h>
#include <math.h>

#define L_SZ 1024
#define STRIDE_ 32
#define WIN 8
#define PNUM 31

// LDS row strides (in shorts). dword strides = 36/68 = 4 mod 32 -> 2-way banks (free).
#define X1TS 72
#define CAS  136

typedef __attribute__((ext_vector_type(8))) short short8;
typedef __attribute__((ext_vector_type(4))) short short4v;
typedef __attribute__((ext_vector_type(4))) float f32x4;

#define MFMA16(a, b, c) __builtin_amdgcn_mfma_f32_16x16x32_bf16(a, b, c, 0, 0, 0)

__device__ __forceinline__ float sigf(float x) { return 1.0f / (1.0f + __expf(-x)); }
__device__ __forceinline__ float tanhfast(float x) {
    float ax = fabsf(x);
    float t = __expf(-2.0f * ax);
    return copysignf((1.0f - t) / (1.0f + t), x);
}
__device__ __forceinline__ short f2bf(float f) {
    __hip_bfloat16 h = __float2bfloat16(f);   // RNE
    return *reinterpret_cast<short*>(&h);
}
__device__ __forceinline__ float bf2f(short s) {
    __hip_bfloat16 h = *reinterpret_cast<__hip_bfloat16*>(&s);
    return __bfloat162float(h);
}
__device__ __forceinline__ float dot4(float4 a, float4 b) {
    return a.x * b.x + a.y * b.y + a.z * b.z + a.w * b.w;
}
__device__ __forceinline__ float f4c(float4 v, int k) {
    return k == 0 ? v.x : (k == 1 ? v.y : (k == 2 ? v.z : v.w));
}
__device__ __forceinline__ void fma4(float4& acc, float s, float4 v) {
    acc.x += s * v.x; acc.y += s * v.y; acc.z += s * v.z; acc.w += s * v.w;
}

// ---------------------------------------------------------------------------
// adjn[i][j] = sigmoid(ew[i][j]) * mask(|i-j|<=8, i!=j) * deg_inv[i]
// ---------------------------------------------------------------------------
__global__ void adj_kernel(const float* __restrict__ ew, float* __restrict__ adjn) {
    int i = threadIdx.x;
    if (i >= 64) return;
    float sum = 0.f;
    for (int j = 0; j < 64; ++j) {
        int d = i - j; d = d < 0 ? -d : d;
        float a = (d <= WIN && d != 0) ? sigf(ew[i * 64 + j]) : 0.f;
        sum += a;
    }
    float dinv = (sum > 0.f) ? 1.0f / sum : 0.f;
    for (int j = 0; j < 64; ++j) {
        int d = i - j; d = d < 0 ? -d : d;
        float a = (d <= WIN && d != 0) ? sigf(ew[i * 64 + j]) : 0.f;
        adjn[i * 64 + j] = a * dinv;
    }
}

// ---------------------------------------------------------------------------
// prep: blocks 0..895 LSTM weight transposes; 896..905: MFMA B-fragments.
// ---------------------------------------------------------------------------
__global__ void prep_kernel(const float* __restrict__ Wih0, const float* __restrict__ Whh0,
                            const float* __restrict__ Wih1, const float* __restrict__ Whh1,
                            const float* __restrict__ adjn,
                            const float* __restrict__ Ws2, const float* __restrict__ Wn2,
                            float* __restrict__ Wih0T, float* __restrict__ Whh0T,
                            float* __restrict__ Wih1T, float* __restrict__ Whh1T,
                            short* __restrict__ adjfG, short* __restrict__ wcatfG) {
    int bid = blockIdx.x, tid = threadIdx.x;
    if (bid >= 896) {
        int t = (bid - 896) * 256 + tid;
        if (t >= 2432) return;
        int f = t >> 6, l = t & 63;
        int q = l >> 4, l15 = l & 15;
        short8 v;
        if (f < 6) {
            const int ntT[6] = {0, 1, 1, 2, 2, 3};
            const int ksT[6] = {0, 0, 1, 0, 1, 1};
            int row = l15 + 16 * ntT[f], col = 8 * q + 32 * ksT[f];
            #pragma unroll
            for (int e = 0; e < 8; ++e)
                v[e] = f2bf(adjn[row * 64 + col + e]);
            *(short8*)(adjfG + ((size_t)f * 64 + l) * 8) = v;
        } else {
            int fi = f - 6;
            int isLo = fi >= 16;
            int ff = isLo ? fi - 16 : fi;
            int nt = ff >> 2, ks = ff & 3;
            int oo = l15 + 16 * nt;
            #pragma unroll
            for (int e = 0; e < 8; ++e) {
                int k = 32 * ks + 8 * q + e;
                float src = (k < 64) ? Ws2[oo * 64 + k] : Wn2[oo * 64 + (k - 64)];
                short hi = f2bf(src);
                v[e] = isLo ? f2bf(src - bf2f(hi)) : hi;
            }
            *(short8*)(wcatfG + ((size_t)fi * 64 + l) * 8) = v;
        }
        return;
    }
    int e = bid * 256 + tid;
    if (e < 32768) {
        int k = e >> 9, j = e & 511;
        Wih0T[e] = Wih0[j * 64 + k];
    } else if (e < 98304) {
        int q = e - 32768; int k = q >> 9, j = q & 511;
        Whh0T[q] = Whh0[j * 128 + k];
    } else if (e < 163840) {
        int q = e - 98304; int k = q >> 9, j = q & 511;
        Wih1T[q] = Wih1[j * 128 + k];
    } else if (e < 229376) {
        int q = e - 163840; int k = q >> 9, j = q & 511;
        Whh1T[q] = Whh1[j * 128 + k];
    }
}

// ---------------------------------------------------------------------------
// Persistent fused SAGE via bf16 MFMA: 1024 blocks x 31 patches, 4 blocks/CU.
// Numerics bit-identical to R10/R11.
// ---------------------------------------------------------------------------
__launch_bounds__(256, 4)
__global__ void sage_mfma(const float* __restrict__ I, const float* __restrict__ Q,
                          const float* __restrict__ adjn,
                          const float* __restrict__ Wn1, const float* __restrict__ bn1,
                          const float* __restrict__ Ws1, const float* __restrict__ bs1,
                          const float* __restrict__ bn2, const float* __restrict__ bs2,
                          const short* __restrict__ adjfG, const short* __restrict__ wcatfG,
                          float* __restrict__ feats) {
    __shared__ __align__(16) short s_x1T[64 * X1TS];   // x1^T [o][i] bf16
    __shared__ __align__(16) short s_cat[64 * CAS];    // [i][0..63:x1, 64..127:n1] bf16
    __shared__ __align__(16) float s_x0[128];
    __shared__ __align__(16) float s_n0[128];
    __shared__ __align__(16) float s_part[4][64];

    const int tid = threadIdx.x;
    const int w = tid >> 6, l = tid & 63, q = l >> 4, l15 = l & 15;

    // ---- lifetime VGPR fragments (patch- and wave-invariant) ----
    short8 adjf[6];
    #pragma unroll
    for (int f = 0; f < 6; ++f)
        adjf[f] = *(const short8*)(adjfG + ((size_t)f * 64 + l) * 8);
    short8 whf[16], wlf[16];
    #pragma unroll
    for (int f = 0; f < 16; ++f) {
        whf[f] = *(const short8*)(wcatfG + ((size_t)f * 64 + l) * 8);
        wlf[f] = *(const short8*)(wcatfG + ((size_t)(f + 16) * 64 + l) * 8);
    }

    for (int it = 0; it < 31; ++it) {
        const int m = blockIdx.x + it * 1024;
        const int b = m / PNUM, p = m % PNUM;
        const float* Ibase = I + (size_t)b * L_SZ + p * STRIDE_;
        const float* Qbase = Q + (size_t)b * L_SZ + p * STRIDE_;

        if (tid < 128) {
            int i = tid >> 1, ch = tid & 1;
            s_x0[i * 2 + ch] = ch ? Qbase[i] : Ibase[i];
        }
        __syncthreads();

        // ---- Phase 1a: n0[i][ch] (exact fp32 adj, L1/L2-resident) ----
        if (tid < 128) {
            int i = tid >> 1, ch = tid & 1;
            int jlo = i - WIN; if (jlo < 0) jlo = 0;
            int jhi = i + WIN; if (jhi > 63) jhi = 63;
            float acc = 0.f;
            for (int j = jlo; j <= jhi; ++j)
                acc += adjn[i * 64 + j] * s_x0[j * 2 + ch];
            s_n0[i * 2 + ch] = acc;
        }
        __syncthreads();

        // ---- Phase 1b: x1[i][o] = relu(...), write x1T + catA ----
        {
            int i = tid & 63, oc = tid >> 6;
            float x0a = s_x0[i * 2], x0b = s_x0[i * 2 + 1];
            float n0a = s_n0[i * 2], n0b = s_n0[i * 2 + 1];
            union { short s[16]; short8 v[2]; } pk;
            #pragma unroll
            for (int t = 0; t < 16; ++t) {
                int o = oc * 16 + t;
                float2 wsv = ((const float2*)Ws1)[o];
                float2 wnv = ((const float2*)Wn1)[o];
                float v = bs1[o] + bn1[o] + wsv.x * x0a + wsv.y * x0b
                                          + wnv.x * n0a + wnv.y * n0b;
                v = fmaxf(v, 0.f);
                short bv = f2bf(v);
                s_x1T[o * X1TS + i] = bv;
                pk.s[t] = bv;
            }
            *(short8*)&s_cat[i * CAS + oc * 16]     = pk.v[0];
            *(short8*)&s_cat[i * CAS + oc * 16 + 8] = pk.v[1];
        }
        __syncthreads();

        // ---- MFMA#1: n1^T, band-aware, B-frags from VGPRs ----
        {
            short8 a0 = *(const short8*)&s_x1T[(16 * w + l15) * X1TS + 8 * q];
            short8 a1 = *(const short8*)&s_x1T[(16 * w + l15) * X1TS + 8 * q + 32];
            f32x4 z = {0.f, 0.f, 0.f, 0.f};
            f32x4 c0 = z, c1 = z, c2 = z, c3 = z;
            c0 = MFMA16(a0, adjf[0], c0);
            c1 = MFMA16(a0, adjf[1], c1);
            c1 = MFMA16(a1, adjf[2], c1);
            c2 = MFMA16(a0, adjf[3], c2);
            c2 = MFMA16(a1, adjf[4], c2);
            c3 = MFMA16(a1, adjf[5], c3);
            f32x4 cc[4] = {c0, c1, c2, c3};
            #pragma unroll
            for (int nt = 0; nt < 4; ++nt) {
                short4v nv;
                nv[0] = f2bf(cc[nt][0]); nv[1] = f2bf(cc[nt][1]);
                nv[2] = f2bf(cc[nt][2]); nv[3] = f2bf(cc[nt][3]);
                *(short4v*)&s_cat[(l15 + 16 * nt) * CAS + 64 + 16 * w + 4 * q] = nv;
            }
        }
        __syncthreads();

        // ---- MFMA#2: out2 tile; B = W_hi + W_lo from VGPRs ----
        {
            short8 a2[4];
            #pragma unroll
            for (int ks = 0; ks < 4; ++ks)
                a2[ks] = *(const short8*)&s_cat[(16 * w + l15) * CAS + 32 * ks + 8 * q];
            f32x4 z = {0.f, 0.f, 0.f, 0.f};
            f32x4 acc2[4] = {z, z, z, z};
            #pragma unroll
            for (int nt = 0; nt < 4; ++nt) {
                #pragma unroll
                for (int ks = 0; ks < 4; ++ks) {
                    acc2[nt] = MFMA16(a2[ks], whf[nt * 4 + ks], acc2[nt]);
                    acc2[nt] = MFMA16(a2[ks], wlf[nt * 4 + ks], acc2[nt]);
                }
            }
            float part[4];
            #pragma unroll
            for (int nt = 0; nt < 4; ++nt) {
                int oo = l15 + 16 * nt;
                float bo = bs2[oo] + bn2[oo];
                float s = fmaxf(acc2[nt][0] + bo, 0.f) + fmaxf(acc2[nt][1] + bo, 0.f)
                        + fmaxf(acc2[nt][2] + bo, 0.f) + fmaxf(acc2[nt][3] + bo, 0.f);
                s += __shfl_xor(s, 16);
                s += __shfl_xor(s, 32);
                part[nt] = s;
            }
            if (l < 16) {
                #pragma unroll
                for (int nt = 0; nt < 4; ++nt)
                    s_part[w][l + 16 * nt] = part[nt];
            }
        }
        __syncthreads();
        if (tid < 64)
            feats[(size_t)m * 64 + tid] =
                s_part[0][tid] + s_part[1][tid] + s_part[2][tid] + s_part[3][tid];
    }
}

// ---------------------------------------------------------------------------
// GEMM: C[M x 512] = A[M x K] @ BT[K x 512] + bias1 + bias2  (R8, verified)
// ---------------------------------------------------------------------------
template <int K>
__launch_bounds__(256, 2)
__global__ void gemm512_kernel(const float* __restrict__ A, const float* __restrict__ BT,
                               const float* __restrict__ bias1, const float* __restrict__ bias2,
                               float* __restrict__ C) {
    constexpr int K4 = K / 4;
    __shared__ __align__(16) float s_a[64 * K];
    const int tid = threadIdx.x;
    const int m0 = blockIdx.x * 64;
    const int j0 = blockIdx.y * 128;

    const float4* Ag = (const float4*)A;
    for (int e = tid; e < 16 * K; e += 256) {
        int row = e / K4, c = e % K4;
        ((float4*)s_a)[row * K4 + (c ^ ((row >> 2) & 7))] = Ag[(size_t)(m0 + row) * K4 + c];
    }
    __syncthreads();

    const int ti = tid >> 4, tj = tid & 15;
    const int swz = ti & 7;
    const int j = j0 + tj * 8;
    const int jb = (j0 >> 2) + tj * 2;
    const float4* BT4 = (const float4*)BT;

    float4 accL[4], accH[4];
    #pragma unroll
    for (int ii = 0; ii < 4; ++ii) {
        accL[ii] = make_float4(0.f, 0.f, 0.f, 0.f);
        accH[ii] = make_float4(0.f, 0.f, 0.f, 0.f);
    }
    for (int c = 0; c < K4; ++c) {
        float4 a4[4];
        #pragma unroll
        for (int ii = 0; ii < 4; ++ii)
            a4[ii] = ((const float4*)s_a)[(4 * ti + ii) * K4 + (c ^ swz)];
        #pragma unroll
        for (int kk = 0; kk < 4; ++kk) {
            float4 b1 = BT4[(size_t)(c * 4 + kk) * 128 + jb];
            float4 b2 = BT4[(size_t)(c * 4 + kk) * 128 + jb + 1];
            #pragma unroll
            for (int ii = 0; ii < 4; ++ii) {
                float av = f4c(a4[ii], kk);
                fma4(accL[ii], av, b1);
                fma4(accH[ii], av, b2);
            }
        }
    }
    float4 bL = make_float4(bias1[j] + bias2[j], bias1[j + 1] + bias2[j + 1],
                            bias1[j + 2] + bias2[j + 2], bias1[j + 3] + bias2[j + 3]);
    float4 bH = make_float4(bias1[j + 4] + bias2[j + 4], bias1[j + 5] + bias2[j + 5],
                            bias1[j + 6] + bias2[j + 6], bias1[j + 7] + bias2[j + 7]);
    #pragma unroll
    for (int ii = 0; ii < 4; ++ii) {
        size_t row = (size_t)(m0 + 4 * ti + ii);
        float4 oL = make_float4(accL[ii].x + bL.x, accL[ii].y + bL.y,
                                accL[ii].z + bL.z, accL[ii].w + bL.w);
        float4 oH = make_float4(accH[ii].x + bH.x, accH[ii].y + bH.y,
                                accH[ii].z + bH.z, accH[ii].w + bH.w);
        ((float4*)C)[(row * 512 + j) >> 2] = oL;
        ((float4*)C)[(row * 512 + j + 4) >> 2] = oH;
    }
}

// ---------------------------------------------------------------------------
// LSTM recurrence (Whh-only stream; xg precomputed). 256 thr, 2 gates x 4 rows.
// FINAL: run classifier instead of writing h-sequence.
// ---------------------------------------------------------------------------
template <bool FINAL>
__launch_bounds__(256)
__global__ void lstm_rec(const float* __restrict__ xg, const float* __restrict__ WhhT,
                         float* __restrict__ out0,
                         const float* __restrict__ Wc1, const float* __restrict__ bc1,
                         const float* __restrict__ Wc2, const float* __restrict__ bc2,
                         float* __restrict__ out) {
    __shared__ __align__(16) float s_hf[128 * 4];   // [k][r]
    __shared__ float s_c[4][128];
    __shared__ float s_g[4][512];
    __shared__ float s_hid[4][64];
    const int tid = threadIdx.x;
    const int b0 = blockIdx.x * 4;

    s_hf[tid] = 0.f; s_hf[tid + 256] = 0.f;
    ((float*)s_c)[tid] = 0.f; ((float*)s_c)[tid + 256] = 0.f;
    __syncthreads();

    for (int t = 0; t < 31; ++t) {
        float a0[4], a1[4];
        #pragma unroll
        for (int r = 0; r < 4; ++r) {
            size_t row = ((size_t)(b0 + r) * PNUM + t) * 512;
            a0[r] = xg[row + tid];
            a1[r] = xg[row + 256 + tid];
        }
        #pragma unroll 8
        for (int k = 0; k < 128; ++k) {
            float w0 = WhhT[(size_t)k * 512 + tid];
            float w1 = WhhT[(size_t)k * 512 + 256 + tid];
            float4 hv = *(const float4*)&s_hf[k * 4];
            a0[0] += hv.x * w0; a0[1] += hv.y * w0; a0[2] += hv.z * w0; a0[3] += hv.w * w0;
            a1[0] += hv.x * w1; a1[1] += hv.y * w1; a1[2] += hv.z * w1; a1[3] += hv.w * w1;
        }
        #pragma unroll
        for (int r = 0; r < 4; ++r) { s_g[r][tid] = a0[r]; s_g[r][tid + 256] = a1[r]; }
        __syncthreads();

        #pragma unroll
        for (int qq = 0; qq < 2; ++qq) {
            int idx = tid + qq * 256;
            int r = idx >> 7, u = idx & 127;
            float gi = s_g[r][u], gf = s_g[r][128 + u];
            float gg = s_g[r][256 + u], go = s_g[r][384 + u];
            float c = sigf(gf) * s_c[r][u] + sigf(gi) * tanhfast(gg);
            float h = sigf(go) * tanhfast(c);
            s_c[r][u] = c;
            s_hf[u * 4 + r] = h;
            if (!FINAL)
                out0[((size_t)(b0 + r) * PNUM + t) * 128 + u] = h;
        }
        __syncthreads();
    }

    if (FINAL) {
        // classifier: hid = relu(h @ Wc1^T + bc1); out = hid @ Wc2^T + bc2
        {
            int r = tid >> 6, u = tid & 63;
            float acc = bc1[u];
            const float* wv = Wc1 + (size_t)u * 128;
            #pragma unroll 8
            for (int k = 0; k < 128; ++k) acc += wv[k] * s_hf[k * 4 + r];
            s_hid[r][u] = fmaxf(acc, 0.f);
        }
        __syncthreads();
        if (tid < 44) {
            int r = tid / 11, c = tid % 11;
            float acc = bc2[c];
            #pragma unroll
            for (int u = 0; u < 64; ++u) acc += Wc2[c * 64 + u] * s_hid[r][u];
            out[(size_t)(b0 + r) * 11 + c] = acc;
        }
    }
}

// ---------------------------------------------------------------------------
extern "C" void kernel_launch(void* const* d_in, const int* in_sizes, int n_in,
                              void* d_out, int out_size, void* d_ws, size_t ws_size,
                              hipStream_t stream) {
    (void)in_sizes; (void)n_in; (void)out_size; (void)ws_size;
    const float* I    = (const float*)d_in[0];
    const float* Q    = (const float*)d_in[1];
    const float* ew   = (const float*)d_in[2];
    const float* Wn1  = (const float*)d_in[3];
    const float* bn1  = (const float*)d_in[4];
    const float* Ws1  = (const float*)d_in[5];
    const float* bs1  = (const float*)d_in[6];
    const float* Wn2  = (const float*)d_in[7];
    const float* bn2  = (const float*)d_in[8];
    const float* Ws2  = (const float*)d_in[9];
    const float* bs2  = (const float*)d_in[10];
    const float* Wih0 = (const float*)d_in[11];
    const float* Whh0 = (const float*)d_in[12];
    const float* bih0 = (const float*)d_in[13];
    const float* bhh0 = (const float*)d_in[14];
    const float* Wih1 = (const float*)d_in[15];
    const float* Whh1 = (const float*)d_in[16];
    const float* bih1 = (const float*)d_in[17];
    const float* bhh1 = (const float*)d_in[18];
    const float* Wc1  = (const float*)d_in[19];
    const float* bc1  = (const float*)d_in[20];
    const float* Wc2  = (const float*)d_in[21];
    const float* bc2  = (const float*)d_in[22];
    float* out = (float*)d_out;

    // workspace (floats): ~90.2 MB total (R1-R4 evidenced this size works)
    float* wsp   = (float*)d_ws;
    float* adjn  = wsp;                           // 4096
    float* WihT0 = adjn  + 4096;                  // 32768
    float* WhhT0 = WihT0 + 32768;                 // 65536
    float* WihT1 = WhhT0 + 65536;                 // 65536
    float* WhhT1 = WihT1 + 65536;                 // 65536
    short* adjfG  = (short*)(WhhT1 + 65536);      // 3072 shorts
    short* wcatfG = adjfG + 3072;                 // 16384 shorts (9728 floats total)
    float* feats = WhhT1 + 65536 + 9728;          // 2031616
    float* out0  = feats + 2031616;               // 4063232
    float* xg    = out0  + 4063232;               // 16252928 (shared by both layers)

    adj_kernel<<<1, 64, 0, stream>>>(ew, adjn);
    prep_kernel<<<906, 256, 0, stream>>>(Wih0, Whh0, Wih1, Whh1, adjn, Ws2, Wn2,
                                         WihT0, WhhT0, WihT1, WhhT1, adjfG, wcatfG);
    sage_mfma<<<1024, 256, 0, stream>>>(I, Q, adjn, Wn1, bn1, Ws1, bs1,
                                        bn2, bs2, adjfG, wcatfG, feats);
    gemm512_kernel<64><<<dim3(496, 4), 256, 0, stream>>>(feats, WihT0, bih0, bhh0, xg);
    lstm_rec<false><<<256, 256, 0, stream>>>(xg, WhhT0, out0,
                                             nullptr, nullptr, nullptr, nullptr, nullptr);
    gemm512_kernel<128><<<dim3(496, 4), 256, 0, stream>>>(out0, WihT1, bih1, bhh1, xg);
    lstm_rec<true><<<256, 256, 0, stream>>>(xg, WhhT1, nullptr,
                                            Wc1, bc1, Wc2, bc2, out);
}

// Round 13
// 839.217 us; speedup vs baseline: 1.7418x; 1.7418x over previous
//
#include <hip/hip_runtime.h>
#include <hip/hip_bf16.h>
#include <math.h>

#define L_SZ 1024
#define STRIDE_ 32
#define WIN 8
#define PNUM 31

// LDS row strides (in shorts). dword strides = 36/68 = 4 mod 32 -> 2-way banks (free).
#define X1TS 72
#define CAS  136

typedef __attribute__((ext_vector_type(8))) short short8;
typedef __attribute__((ext_vector_type(4))) short short4v;
typedef __attribute__((ext_vector_type(4))) float f32x4;

#define MFMA16(a, b, c) __builtin_amdgcn_mfma_f32_16x16x32_bf16(a, b, c, 0, 0, 0)

__device__ __forceinline__ float sigf(float x) { return 1.0f / (1.0f + __expf(-x)); }
__device__ __forceinline__ float tanhfast(float x) {
    float ax = fabsf(x);
    float t = __expf(-2.0f * ax);
    return copysignf((1.0f - t) / (1.0f + t), x);
}
__device__ __forceinline__ short f2bf(float f) {
    __hip_bfloat16 h = __float2bfloat16(f);   // RNE
    return *reinterpret_cast<short*>(&h);
}
__device__ __forceinline__ float bf2f(short s) {
    __hip_bfloat16 h = *reinterpret_cast<__hip_bfloat16*>(&s);
    return __bfloat162float(h);
}
__device__ __forceinline__ float f4c(float4 v, int k) {
    return k == 0 ? v.x : (k == 1 ? v.y : (k == 2 ? v.z : v.w));
}
__device__ __forceinline__ void fma4(float4& acc, float s, float4 v) {
    acc.x += s * v.x; acc.y += s * v.y; acc.z += s * v.z; acc.w += s * v.w;
}

// ---------------------------------------------------------------------------
// adjn[i][j] = sigmoid(ew[i][j]) * mask(|i-j|<=8, i!=j) * deg_inv[i]
// ---------------------------------------------------------------------------
__global__ void adj_kernel(const float* __restrict__ ew, float* __restrict__ adjn) {
    int i = threadIdx.x;
    if (i >= 64) return;
    float sum = 0.f;
    for (int j = 0; j < 64; ++j) {
        int d = i - j; d = d < 0 ? -d : d;
        float a = (d <= WIN && d != 0) ? sigf(ew[i * 64 + j]) : 0.f;
        sum += a;
    }
    float dinv = (sum > 0.f) ? 1.0f / sum : 0.f;
    for (int j = 0; j < 64; ++j) {
        int d = i - j; d = d < 0 ? -d : d;
        float a = (d <= WIN && d != 0) ? sigf(ew[i * 64 + j]) : 0.f;
        adjn[i * 64 + j] = a * dinv;
    }
}

// ---------------------------------------------------------------------------
// prep: blocks 0..895 LSTM weight transposes; 896..905: MFMA B-fragments.
// ---------------------------------------------------------------------------
__global__ void prep_kernel(const float* __restrict__ Wih0, const float* __restrict__ Whh0,
                            const float* __restrict__ Wih1, const float* __restrict__ Whh1,
                            const float* __restrict__ adjn,
                            const float* __restrict__ Ws2, const float* __restrict__ Wn2,
                            float* __restrict__ Wih0T, float* __restrict__ Whh0T,
                            float* __restrict__ Wih1T, float* __restrict__ Whh1T,
                            short* __restrict__ adjfG, short* __restrict__ wcatfG) {
    int bid = blockIdx.x, tid = threadIdx.x;
    if (bid >= 896) {
        int t = (bid - 896) * 256 + tid;
        if (t >= 2432) return;
        int f = t >> 6, l = t & 63;
        int q = l >> 4, l15 = l & 15;
        short8 v;
        if (f < 6) {
            const int ntT[6] = {0, 1, 1, 2, 2, 3};
            const int ksT[6] = {0, 0, 1, 0, 1, 1};
            int row = l15 + 16 * ntT[f], col = 8 * q + 32 * ksT[f];
            #pragma unroll
            for (int e = 0; e < 8; ++e)
                v[e] = f2bf(adjn[row * 64 + col + e]);
            *(short8*)(adjfG + ((size_t)f * 64 + l) * 8) = v;
        } else {
            int fi = f - 6;
            int isLo = fi >= 16;
            int ff = isLo ? fi - 16 : fi;
            int nt = ff >> 2, ks = ff & 3;
            int oo = l15 + 16 * nt;
            #pragma unroll
            for (int e = 0; e < 8; ++e) {
                int k = 32 * ks + 8 * q + e;
                float src = (k < 64) ? Ws2[oo * 64 + k] : Wn2[oo * 64 + (k - 64)];
                short hi = f2bf(src);
                v[e] = isLo ? f2bf(src - bf2f(hi)) : hi;
            }
            *(short8*)(wcatfG + ((size_t)fi * 64 + l) * 8) = v;
        }
        return;
    }
    int e = bid * 256 + tid;
    if (e < 32768) {
        int k = e >> 9, j = e & 511;
        Wih0T[e] = Wih0[j * 64 + k];
    } else if (e < 98304) {
        int q = e - 32768; int k = q >> 9, j = q & 511;
        Whh0T[q] = Whh0[j * 128 + k];
    } else if (e < 163840) {
        int q = e - 98304; int k = q >> 9, j = q & 511;
        Wih1T[q] = Wih1[j * 128 + k];
    } else if (e < 229376) {
        int q = e - 163840; int k = q >> 9, j = q & 511;
        Whh1T[q] = Whh1[j * 128 + k];
    }
}

// ---------------------------------------------------------------------------
// Persistent fused SAGE via bf16 MFMA: 512 blocks x 62 patches, 2 blocks/CU.
// EXACT R11 configuration (357 us, VGPR=128, no spill). Do NOT raise the
// occupancy bound: 38 persistent frags (152 VGPRs) spill below cap 256
// (R12 evidence: cap 128 -> 2.5 GB scratch traffic, 911 us).
// ---------------------------------------------------------------------------
__launch_bounds__(256, 2)
__global__ void sage_mfma(const float* __restrict__ I, const float* __restrict__ Q,
                          const float* __restrict__ adjn,
                          const float* __restrict__ Wn1, const float* __restrict__ bn1,
                          const float* __restrict__ Ws1, const float* __restrict__ bs1,
                          const float* __restrict__ bn2, const float* __restrict__ bs2,
                          const short* __restrict__ adjfG, const short* __restrict__ wcatfG,
                          float* __restrict__ feats) {
    __shared__ __align__(16) short s_x1T[64 * X1TS];   // x1^T [o][i] bf16
    __shared__ __align__(16) short s_cat[64 * CAS];    // [i][0..63:x1, 64..127:n1] bf16
    __shared__ __align__(16) float s_x0[128];
    __shared__ __align__(16) float s_n0[128];
    __shared__ __align__(16) float s_part[4][64];

    const int tid = threadIdx.x;
    const int w = tid >> 6, l = tid & 63, q = l >> 4, l15 = l & 15;

    // ---- lifetime VGPR fragments (patch- and wave-invariant) ----
    short8 adjf[6];
    #pragma unroll
    for (int f = 0; f < 6; ++f)
        adjf[f] = *(const short8*)(adjfG + ((size_t)f * 64 + l) * 8);
    short8 whf[16], wlf[16];
    #pragma unroll
    for (int f = 0; f < 16; ++f) {
        whf[f] = *(const short8*)(wcatfG + ((size_t)f * 64 + l) * 8);
        wlf[f] = *(const short8*)(wcatfG + ((size_t)(f + 16) * 64 + l) * 8);
    }

    for (int it = 0; it < 62; ++it) {
        const int m = blockIdx.x + it * 512;
        const int b = m / PNUM, p = m % PNUM;
        const float* Ibase = I + (size_t)b * L_SZ + p * STRIDE_;
        const float* Qbase = Q + (size_t)b * L_SZ + p * STRIDE_;

        if (tid < 128) {
            int i = tid >> 1, ch = tid & 1;
            s_x0[i * 2 + ch] = ch ? Qbase[i] : Ibase[i];
        }
        __syncthreads();

        // ---- Phase 1a: n0[i][ch] (exact fp32 adj, L1/L2-resident) ----
        if (tid < 128) {
            int i = tid >> 1, ch = tid & 1;
            int jlo = i - WIN; if (jlo < 0) jlo = 0;
            int jhi = i + WIN; if (jhi > 63) jhi = 63;
            float acc = 0.f;
            for (int j = jlo; j <= jhi; ++j)
                acc += adjn[i * 64 + j] * s_x0[j * 2 + ch];
            s_n0[i * 2 + ch] = acc;
        }
        __syncthreads();

        // ---- Phase 1b: x1[i][o] = relu(...), write x1T + catA ----
        {
            int i = tid & 63, oc = tid >> 6;
            float x0a = s_x0[i * 2], x0b = s_x0[i * 2 + 1];
            float n0a = s_n0[i * 2], n0b = s_n0[i * 2 + 1];
            union { short s[16]; short8 v[2]; } pk;
            #pragma unroll
            for (int t = 0; t < 16; ++t) {
                int o = oc * 16 + t;
                float2 wsv = ((const float2*)Ws1)[o];
                float2 wnv = ((const float2*)Wn1)[o];
                float v = bs1[o] + bn1[o] + wsv.x * x0a + wsv.y * x0b
                                          + wnv.x * n0a + wnv.y * n0b;
                v = fmaxf(v, 0.f);
                short bv = f2bf(v);
                s_x1T[o * X1TS + i] = bv;
                pk.s[t] = bv;
            }
            *(short8*)&s_cat[i * CAS + oc * 16]     = pk.v[0];
            *(short8*)&s_cat[i * CAS + oc * 16 + 8] = pk.v[1];
        }
        __syncthreads();

        // ---- MFMA#1: n1^T, band-aware, B-frags from VGPRs ----
        {
            short8 a0 = *(const short8*)&s_x1T[(16 * w + l15) * X1TS + 8 * q];
            short8 a1 = *(const short8*)&s_x1T[(16 * w + l15) * X1TS + 8 * q + 32];
            f32x4 z = {0.f, 0.f, 0.f, 0.f};
            f32x4 c0 = z, c1 = z, c2 = z, c3 = z;
            c0 = MFMA16(a0, adjf[0], c0);
            c1 = MFMA16(a0, adjf[1], c1);
            c1 = MFMA16(a1, adjf[2], c1);
            c2 = MFMA16(a0, adjf[3], c2);
            c2 = MFMA16(a1, adjf[4], c2);
            c3 = MFMA16(a1, adjf[5], c3);
            f32x4 cc[4] = {c0, c1, c2, c3};
            #pragma unroll
            for (int nt = 0; nt < 4; ++nt) {
                short4v nv;
                nv[0] = f2bf(cc[nt][0]); nv[1] = f2bf(cc[nt][1]);
                nv[2] = f2bf(cc[nt][2]); nv[3] = f2bf(cc[nt][3]);
                *(short4v*)&s_cat[(l15 + 16 * nt) * CAS + 64 + 16 * w + 4 * q] = nv;
            }
        }
        __syncthreads();

        // ---- MFMA#2: out2 tile; B = W_hi + W_lo from VGPRs ----
        {
            short8 a2[4];
            #pragma unroll
            for (int ks = 0; ks < 4; ++ks)
                a2[ks] = *(const short8*)&s_cat[(16 * w + l15) * CAS + 32 * ks + 8 * q];
            f32x4 z = {0.f, 0.f, 0.f, 0.f};
            f32x4 acc2[4] = {z, z, z, z};
            #pragma unroll
            for (int nt = 0; nt < 4; ++nt) {
                #pragma unroll
                for (int ks = 0; ks < 4; ++ks) {
                    acc2[nt] = MFMA16(a2[ks], whf[nt * 4 + ks], acc2[nt]);
                    acc2[nt] = MFMA16(a2[ks], wlf[nt * 4 + ks], acc2[nt]);
                }
            }
            float part[4];
            #pragma unroll
            for (int nt = 0; nt < 4; ++nt) {
                int oo = l15 + 16 * nt;
                float bo = bs2[oo] + bn2[oo];
                float s = fmaxf(acc2[nt][0] + bo, 0.f) + fmaxf(acc2[nt][1] + bo, 0.f)
                        + fmaxf(acc2[nt][2] + bo, 0.f) + fmaxf(acc2[nt][3] + bo, 0.f);
                s += __shfl_xor(s, 16);
                s += __shfl_xor(s, 32);
                part[nt] = s;
            }
            if (l < 16) {
                #pragma unroll
                for (int nt = 0; nt < 4; ++nt)
                    s_part[w][l + 16 * nt] = part[nt];
            }
        }
        __syncthreads();
        if (tid < 64)
            feats[(size_t)m * 64 + tid] =
                s_part[0][tid] + s_part[1][tid] + s_part[2][tid] + s_part[3][tid];
    }
}

// ---------------------------------------------------------------------------
// GEMM: C[M x 512] = A[M x K] @ BT[K x 512] + bias1 + bias2  (verified R8/R12)
// ---------------------------------------------------------------------------
template <int K>
__launch_bounds__(256, 2)
__global__ void gemm512_kernel(const float* __restrict__ A, const float* __restrict__ BT,
                               const float* __restrict__ bias1, const float* __restrict__ bias2,
                               float* __restrict__ C) {
    constexpr int K4 = K / 4;
    __shared__ __align__(16) float s_a[64 * K];
    const int tid = threadIdx.x;
    const int m0 = blockIdx.x * 64;
    const int j0 = blockIdx.y * 128;

    const float4* Ag = (const float4*)A;
    for (int e = tid; e < 16 * K; e += 256) {
        int row = e / K4, c = e % K4;
        ((float4*)s_a)[row * K4 + (c ^ ((row >> 2) & 7))] = Ag[(size_t)(m0 + row) * K4 + c];
    }
    __syncthreads();

    const int ti = tid >> 4, tj = tid & 15;
    const int swz = ti & 7;
    const int j = j0 + tj * 8;
    const int jb = (j0 >> 2) + tj * 2;
    const float4* BT4 = (const float4*)BT;

    float4 accL[4], accH[4];
    #pragma unroll
    for (int ii = 0; ii < 4; ++ii) {
        accL[ii] = make_float4(0.f, 0.f, 0.f, 0.f);
        accH[ii] = make_float4(0.f, 0.f, 0.f, 0.f);
    }
    for (int c = 0; c < K4; ++c) {
        float4 a4[4];
        #pragma unroll
        for (int ii = 0; ii < 4; ++ii)
            a4[ii] = ((const float4*)s_a)[(4 * ti + ii) * K4 + (c ^ swz)];
        #pragma unroll
        for (int kk = 0; kk < 4; ++kk) {
            float4 b1 = BT4[(size_t)(c * 4 + kk) * 128 + jb];
            float4 b2 = BT4[(size_t)(c * 4 + kk) * 128 + jb + 1];
            #pragma unroll
            for (int ii = 0; ii < 4; ++ii) {
                float av = f4c(a4[ii], kk);
                fma4(accL[ii], av, b1);
                fma4(accH[ii], av, b2);
            }
        }
    }
    float4 bL = make_float4(bias1[j] + bias2[j], bias1[j + 1] + bias2[j + 1],
                            bias1[j + 2] + bias2[j + 2], bias1[j + 3] + bias2[j + 3]);
    float4 bH = make_float4(bias1[j + 4] + bias2[j + 4], bias1[j + 5] + bias2[j + 5],
                            bias1[j + 6] + bias2[j + 6], bias1[j + 7] + bias2[j + 7]);
    #pragma unroll
    for (int ii = 0; ii < 4; ++ii) {
        size_t row = (size_t)(m0 + 4 * ti + ii);
        float4 oL = make_float4(accL[ii].x + bL.x, accL[ii].y + bL.y,
                                accL[ii].z + bL.z, accL[ii].w + bL.w);
        float4 oH = make_float4(accH[ii].x + bH.x, accH[ii].y + bH.y,
                                accH[ii].z + bH.z, accH[ii].w + bH.w);
        ((float4*)C)[(row * 512 + j) >> 2] = oL;
        ((float4*)C)[(row * 512 + j + 4) >> 2] = oH;
    }
}

// ---------------------------------------------------------------------------
// LSTM recurrence v3: 512 thr (8 waves = 2/SIMD), one gate/thread x 4 rows.
// Whh-only stream (xg precomputed by gemm512). Same accumulation order as R12.
// ---------------------------------------------------------------------------
template <bool FINAL>
__launch_bounds__(512)
__global__ void lstm_rec(const float* __restrict__ xg, const float* __restrict__ WhhT,
                         float* __restrict__ out0,
                         const float* __restrict__ Wc1, const float* __restrict__ bc1,
                         const float* __restrict__ Wc2, const float* __restrict__ bc2,
                         float* __restrict__ out) {
    __shared__ __align__(16) float s_hf[128 * 4];   // [k][r]
    __shared__ float s_c[512];                      // [r*128+u]
    __shared__ float s_g[4][512];
    __shared__ float s_hid[4][64];
    const int tid = threadIdx.x;
    const int b0 = blockIdx.x * 4;

    s_hf[tid] = 0.f;
    s_c[tid] = 0.f;
    __syncthreads();

    for (int t = 0; t < 31; ++t) {
        float a[4];
        #pragma unroll
        for (int r = 0; r < 4; ++r)
            a[r] = xg[((size_t)(b0 + r) * PNUM + t) * 512 + tid];
        const float* wp = WhhT + tid;
        #pragma unroll 8
        for (int k = 0; k < 128; ++k) {
            float w = wp[(size_t)k * 512];          // coalesced within wave
            float4 hv = *(const float4*)&s_hf[k * 4];
            a[0] += hv.x * w; a[1] += hv.y * w; a[2] += hv.z * w; a[3] += hv.w * w;
        }
        #pragma unroll
        for (int r = 0; r < 4; ++r) s_g[r][tid] = a[r];
        __syncthreads();

        {
            int r = tid >> 7, u = tid & 127;
            float gi = s_g[r][u], gf = s_g[r][128 + u];
            float gg = s_g[r][256 + u], go = s_g[r][384 + u];
            float c = sigf(gf) * s_c[tid] + sigf(gi) * tanhfast(gg);
            float h = sigf(go) * tanhfast(c);
            s_c[tid] = c;
            s_hf[u * 4 + r] = h;
            if (!FINAL)
                out0[((size_t)(b0 + r) * PNUM + t) * 128 + u] = h;
        }
        __syncthreads();
    }

    if (FINAL) {
        // classifier: hid = relu(h @ Wc1^T + bc1); out = hid @ Wc2^T + bc2
        if (tid < 256) {
            int r = tid >> 6, u = tid & 63;
            float acc = bc1[u];
            const float* wv = Wc1 + (size_t)u * 128;
            #pragma unroll 8
            for (int k = 0; k < 128; ++k) acc += wv[k] * s_hf[k * 4 + r];
            s_hid[r][u] = fmaxf(acc, 0.f);
        }
        __syncthreads();
        if (tid < 44) {
            int r = tid / 11, c = tid % 11;
            float acc = bc2[c];
            #pragma unroll
            for (int u = 0; u < 64; ++u) acc += Wc2[c * 64 + u] * s_hid[r][u];
            out[(size_t)(b0 + r) * 11 + c] = acc;
        }
    }
}

// ---------------------------------------------------------------------------
extern "C" void kernel_launch(void* const* d_in, const int* in_sizes, int n_in,
                              void* d_out, int out_size, void* d_ws, size_t ws_size,
                              hipStream_t stream) {
    (void)in_sizes; (void)n_in; (void)out_size; (void)ws_size;
    const float* I    = (const float*)d_in[0];
    const float* Q    = (const float*)d_in[1];
    const float* ew   = (const float*)d_in[2];
    const float* Wn1  = (const float*)d_in[3];
    const float* bn1  = (const float*)d_in[4];
    const float* Ws1  = (const float*)d_in[5];
    const float* bs1  = (const float*)d_in[6];
    const float* Wn2  = (const float*)d_in[7];
    const float* bn2  = (const float*)d_in[8];
    const float* Ws2  = (const float*)d_in[9];
    const float* bs2  = (const float*)d_in[10];
    const float* Wih0 = (const float*)d_in[11];
    const float* Whh0 = (const float*)d_in[12];
    const float* bih0 = (const float*)d_in[13];
    const float* bhh0 = (const float*)d_in[14];
    const float* Wih1 = (const float*)d_in[15];
    const float* Whh1 = (const float*)d_in[16];
    const float* bih1 = (const float*)d_in[17];
    const float* bhh1 = (const float*)d_in[18];
    const float* Wc1  = (const float*)d_in[19];
    const float* bc1  = (const float*)d_in[20];
    const float* Wc2  = (const float*)d_in[21];
    const float* bc2  = (const float*)d_in[22];
    float* out = (float*)d_out;

    // workspace (floats): ~90.2 MB
    float* wsp   = (float*)d_ws;
    float* adjn  = wsp;                           // 4096
    float* WihT0 = adjn  + 4096;                  // 32768
    float* WhhT0 = WihT0 + 32768;                 // 65536
    float* WihT1 = WhhT0 + 65536;                 // 65536
    float* WhhT1 = WihT1 + 65536;                 // 65536
    short* adjfG  = (short*)(WhhT1 + 65536);      // 3072 shorts
    short* wcatfG = adjfG + 3072;                 // 16384 shorts (9728 floats total)
    float* feats = WhhT1 + 65536 + 9728;          // 2031616
    float* out0  = feats + 2031616;               // 4063232
    float* xg    = out0  + 4063232;               // 16252928 (shared by both layers)

    adj_kernel<<<1, 64, 0, stream>>>(ew, adjn);
    prep_kernel<<<906, 256, 0, stream>>>(Wih0, Whh0, Wih1, Whh1, adjn, Ws2, Wn2,
                                         WihT0, WhhT0, WihT1, WhhT1, adjfG, wcatfG);
    sage_mfma<<<512, 256, 0, stream>>>(I, Q, adjn, Wn1, bn1, Ws1, bs1,
                                       bn2, bs2, adjfG, wcatfG, feats);
    gemm512_kernel<64><<<dim3(496, 4), 256, 0, stream>>>(feats, WihT0, bih0, bhh0, xg);
    lstm_rec<false><<<256, 512, 0, stream>>>(xg, WhhT0, out0,
                                             nullptr, nullptr, nullptr, nullptr, nullptr);
    gemm512_kernel<128><<<dim3(496, 4), 256, 0, stream>>>(out0, WihT1, bih1, bhh1, xg);
    lstm_rec<true><<<256, 512, 0, stream>>>(xg, WhhT1, nullptr,
                                            Wc1, bc1, Wc2, bc2, out);
}

// Round 14
// 735.844 us; speedup vs baseline: 1.9864x; 1.1405x over previous
//
#include <hip/hip_runtime.h>
#include <hip/hip_bf16.h>
#include <math.h>

#define L_SZ 1024
#define STRIDE_ 32
#define WIN 8
#define PNUM 31

// LDS row strides (in shorts). dword strides = 36/68 = 4 mod 32 -> 2-way banks (free).
#define X1TS 72
#define CAS  136

typedef __attribute__((ext_vector_type(8))) short short8;
typedef __attribute__((ext_vector_type(4))) short short4v;
typedef __attribute__((ext_vector_type(4))) float f32x4;

#define MFMA16(a, b, c) __builtin_amdgcn_mfma_f32_16x16x32_bf16(a, b, c, 0, 0, 0)

__device__ __forceinline__ float sigf(float x) { return 1.0f / (1.0f + __expf(-x)); }
__device__ __forceinline__ float tanhfast(float x) {
    float ax = fabsf(x);
    float t = __expf(-2.0f * ax);
    return copysignf((1.0f - t) / (1.0f + t), x);
}
__device__ __forceinline__ short f2bf(float f) {
    __hip_bfloat16 h = __float2bfloat16(f);   // RNE
    return *reinterpret_cast<short*>(&h);
}
__device__ __forceinline__ float bf2f(short s) {
    __hip_bfloat16 h = *reinterpret_cast<__hip_bfloat16*>(&s);
    return __bfloat162float(h);
}
__device__ __forceinline__ float f4c(float4 v, int k) {
    return k == 0 ? v.x : (k == 1 ? v.y : (k == 2 ? v.z : v.w));
}
__device__ __forceinline__ void fma4(float4& acc, float s, float4 v) {
    acc.x += s * v.x; acc.y += s * v.y; acc.z += s * v.z; acc.w += s * v.w;
}

// ---------------------------------------------------------------------------
// adjn[i][j] = sigmoid(ew[i][j]) * mask(|i-j|<=8, i!=j) * deg_inv[i]
// ---------------------------------------------------------------------------
__global__ void adj_kernel(const float* __restrict__ ew, float* __restrict__ adjn) {
    int i = threadIdx.x;
    if (i >= 64) return;
    float sum = 0.f;
    for (int j = 0; j < 64; ++j) {
        int d = i - j; d = d < 0 ? -d : d;
        float a = (d <= WIN && d != 0) ? sigf(ew[i * 64 + j]) : 0.f;
        sum += a;
    }
    float dinv = (sum > 0.f) ? 1.0f / sum : 0.f;
    for (int j = 0; j < 64; ++j) {
        int d = i - j; d = d < 0 ? -d : d;
        float a = (d <= WIN && d != 0) ? sigf(ew[i * 64 + j]) : 0.f;
        adjn[i * 64 + j] = a * dinv;
    }
}

// ---------------------------------------------------------------------------
// prep:
//   blocks   0..127 : Wih0T [64][512]
//   blocks 128..383 : Wih1T [128][512]
//   blocks 384..393 : sage B-fragments (adj + wcat hi/lo)
//   blocks 394..457 : Whh0 MFMA B-fragments hi/lo (per-lane order)
//   blocks 458..521 : Whh1 MFMA B-fragments hi/lo
// ---------------------------------------------------------------------------
__global__ void prep_kernel(const float* __restrict__ Wih0, const float* __restrict__ Whh0,
                            const float* __restrict__ Wih1, const float* __restrict__ Whh1,
                            const float* __restrict__ adjn,
                            const float* __restrict__ Ws2, const float* __restrict__ Wn2,
                            float* __restrict__ Wih0T, float* __restrict__ Wih1T,
                            short* __restrict__ adjfG, short* __restrict__ wcatfG,
                            short* __restrict__ whhf0G, short* __restrict__ whhf1G) {
    int bid = blockIdx.x, tid = threadIdx.x;
    if (bid < 128) {                         // Wih0T [64][512] <- Wih0 [512][64]
        int e = bid * 256 + tid;
        int k = e >> 9, j = e & 511;
        Wih0T[e] = Wih0[j * 64 + k];
        return;
    }
    if (bid < 384) {                         // Wih1T [128][512] <- Wih1 [512][128]
        int e = (bid - 128) * 256 + tid;
        int k = e >> 9, j = e & 511;
        Wih1T[e] = Wih1[j * 128 + k];
        return;
    }
    if (bid < 394) {                         // sage fragments
        int t = (bid - 384) * 256 + tid;
        if (t >= 2432) return;
        int f = t >> 6, l = t & 63;
        int q = l >> 4, l15 = l & 15;
        short8 v;
        if (f < 6) {
            const int ntT[6] = {0, 1, 1, 2, 2, 3};
            const int ksT[6] = {0, 0, 1, 0, 1, 1};
            int row = l15 + 16 * ntT[f], col = 8 * q + 32 * ksT[f];
            #pragma unroll
            for (int e = 0; e < 8; ++e)
                v[e] = f2bf(adjn[row * 64 + col + e]);
            *(short8*)(adjfG + ((size_t)f * 64 + l) * 8) = v;
        } else {
            int fi = f - 6;
            int isLo = fi >= 16;
            int ff = isLo ? fi - 16 : fi;
            int nt = ff >> 2, ks = ff & 3;
            int oo = l15 + 16 * nt;
            #pragma unroll
            for (int e = 0; e < 8; ++e) {
                int k = 32 * ks + 8 * q + e;
                float src = (k < 64) ? Ws2[oo * 64 + k] : Wn2[oo * 64 + (k - 64)];
                short hi = f2bf(src);
                v[e] = isLo ? f2bf(src - bf2f(hi)) : hi;
            }
            *(short8*)(wcatfG + ((size_t)fi * 64 + l) * 8) = v;
        }
        return;
    }
    // Whh fragments: layer from block range; 16384 lane-frags per layer
    {
        int layer = (bid < 458) ? 0 : 1;
        int base = layer ? 458 : 394;
        const float* Whh = layer ? Whh1 : Whh0;
        short* dst = layer ? whhf1G : whhf0G;
        int t = (bid - base) * 256 + tid;    // 0..16383
        int frag = t >> 6, l = t & 63;
        int hl = frag & 1, ks = (frag >> 1) & 3, NT = frag >> 3;   // NT 0..31
        int g = NT * 16 + (l & 15);
        int kbase = ks * 32 + (l >> 4) * 8;
        short8 v;
        #pragma unroll
        for (int e = 0; e < 8; ++e) {
            float src = Whh[(size_t)g * 128 + kbase + e];
            short hi = f2bf(src);
            v[e] = hl ? f2bf(src - bf2f(hi)) : hi;
        }
        *(short8*)(dst + (size_t)t * 8) = v;
    }
}

// ---------------------------------------------------------------------------
// Persistent fused SAGE via bf16 MFMA: 512 blocks x 62 patches, 2 blocks/CU.
// EXACT R11/R13 configuration (349 us, VGPR=128, no spill). Do NOT raise the
// occupancy bound (R12: cap 128 -> fragments spill -> 2.5 GB scratch, 911 us).
// ---------------------------------------------------------------------------
__launch_bounds__(256, 2)
__global__ void sage_mfma(const float* __restrict__ I, const float* __restrict__ Q,
                          const float* __restrict__ adjn,
                          const float* __restrict__ Wn1, const float* __restrict__ bn1,
                          const float* __restrict__ Ws1, const float* __restrict__ bs1,
                          const float* __restrict__ bn2, const float* __restrict__ bs2,
                          const short* __restrict__ adjfG, const short* __restrict__ wcatfG,
                          float* __restrict__ feats) {
    __shared__ __align__(16) short s_x1T[64 * X1TS];   // x1^T [o][i] bf16
    __shared__ __align__(16) short s_cat[64 * CAS];    // [i][0..63:x1, 64..127:n1] bf16
    __shared__ __align__(16) float s_x0[128];
    __shared__ __align__(16) float s_n0[128];
    __shared__ __align__(16) float s_part[4][64];

    const int tid = threadIdx.x;
    const int w = tid >> 6, l = tid & 63, q = l >> 4, l15 = l & 15;

    short8 adjf[6];
    #pragma unroll
    for (int f = 0; f < 6; ++f)
        adjf[f] = *(const short8*)(adjfG + ((size_t)f * 64 + l) * 8);
    short8 whf[16], wlf[16];
    #pragma unroll
    for (int f = 0; f < 16; ++f) {
        whf[f] = *(const short8*)(wcatfG + ((size_t)f * 64 + l) * 8);
        wlf[f] = *(const short8*)(wcatfG + ((size_t)(f + 16) * 64 + l) * 8);
    }

    for (int it = 0; it < 62; ++it) {
        const int m = blockIdx.x + it * 512;
        const int b = m / PNUM, p = m % PNUM;
        const float* Ibase = I + (size_t)b * L_SZ + p * STRIDE_;
        const float* Qbase = Q + (size_t)b * L_SZ + p * STRIDE_;

        if (tid < 128) {
            int i = tid >> 1, ch = tid & 1;
            s_x0[i * 2 + ch] = ch ? Qbase[i] : Ibase[i];
        }
        __syncthreads();

        if (tid < 128) {
            int i = tid >> 1, ch = tid & 1;
            int jlo = i - WIN; if (jlo < 0) jlo = 0;
            int jhi = i + WIN; if (jhi > 63) jhi = 63;
            float acc = 0.f;
            for (int j = jlo; j <= jhi; ++j)
                acc += adjn[i * 64 + j] * s_x0[j * 2 + ch];
            s_n0[i * 2 + ch] = acc;
        }
        __syncthreads();

        {
            int i = tid & 63, oc = tid >> 6;
            float x0a = s_x0[i * 2], x0b = s_x0[i * 2 + 1];
            float n0a = s_n0[i * 2], n0b = s_n0[i * 2 + 1];
            union { short s[16]; short8 v[2]; } pk;
            #pragma unroll
            for (int t = 0; t < 16; ++t) {
                int o = oc * 16 + t;
                float2 wsv = ((const float2*)Ws1)[o];
                float2 wnv = ((const float2*)Wn1)[o];
                float v = bs1[o] + bn1[o] + wsv.x * x0a + wsv.y * x0b
                                          + wnv.x * n0a + wnv.y * n0b;
                v = fmaxf(v, 0.f);
                short bv = f2bf(v);
                s_x1T[o * X1TS + i] = bv;
                pk.s[t] = bv;
            }
            *(short8*)&s_cat[i * CAS + oc * 16]     = pk.v[0];
            *(short8*)&s_cat[i * CAS + oc * 16 + 8] = pk.v[1];
        }
        __syncthreads();

        {
            short8 a0 = *(const short8*)&s_x1T[(16 * w + l15) * X1TS + 8 * q];
            short8 a1 = *(const short8*)&s_x1T[(16 * w + l15) * X1TS + 8 * q + 32];
            f32x4 z = {0.f, 0.f, 0.f, 0.f};
            f32x4 c0 = z, c1 = z, c2 = z, c3 = z;
            c0 = MFMA16(a0, adjf[0], c0);
            c1 = MFMA16(a0, adjf[1], c1);
            c1 = MFMA16(a1, adjf[2], c1);
            c2 = MFMA16(a0, adjf[3], c2);
            c2 = MFMA16(a1, adjf[4], c2);
            c3 = MFMA16(a1, adjf[5], c3);
            f32x4 cc[4] = {c0, c1, c2, c3};
            #pragma unroll
            for (int nt = 0; nt < 4; ++nt) {
                short4v nv;
                nv[0] = f2bf(cc[nt][0]); nv[1] = f2bf(cc[nt][1]);
                nv[2] = f2bf(cc[nt][2]); nv[3] = f2bf(cc[nt][3]);
                *(short4v*)&s_cat[(l15 + 16 * nt) * CAS + 64 + 16 * w + 4 * q] = nv;
            }
        }
        __syncthreads();

        {
            short8 a2[4];
            #pragma unroll
            for (int ks = 0; ks < 4; ++ks)
                a2[ks] = *(const short8*)&s_cat[(16 * w + l15) * CAS + 32 * ks + 8 * q];
            f32x4 z = {0.f, 0.f, 0.f, 0.f};
            f32x4 acc2[4] = {z, z, z, z};
            #pragma unroll
            for (int nt = 0; nt < 4; ++nt) {
                #pragma unroll
                for (int ks = 0; ks < 4; ++ks) {
                    acc2[nt] = MFMA16(a2[ks], whf[nt * 4 + ks], acc2[nt]);
                    acc2[nt] = MFMA16(a2[ks], wlf[nt * 4 + ks], acc2[nt]);
                }
            }
            float part[4];
            #pragma unroll
            for (int nt = 0; nt < 4; ++nt) {
                int oo = l15 + 16 * nt;
                float bo = bs2[oo] + bn2[oo];
                float s = fmaxf(acc2[nt][0] + bo, 0.f) + fmaxf(acc2[nt][1] + bo, 0.f)
                        + fmaxf(acc2[nt][2] + bo, 0.f) + fmaxf(acc2[nt][3] + bo, 0.f);
                s += __shfl_xor(s, 16);
                s += __shfl_xor(s, 32);
                part[nt] = s;
            }
            if (l < 16) {
                #pragma unroll
                for (int nt = 0; nt < 4; ++nt)
                    s_part[w][l + 16 * nt] = part[nt];
            }
        }
        __syncthreads();
        if (tid < 64)
            feats[(size_t)m * 64 + tid] =
                s_part[0][tid] + s_part[1][tid] + s_part[2][tid] + s_part[3][tid];
    }
}

// ---------------------------------------------------------------------------
// GEMM: C[M x 512] = A[M x K] @ BT[K x 512] + bias1 + bias2  (verified)
// ---------------------------------------------------------------------------
template <int K>
__launch_bounds__(256, 2)
__global__ void gemm512_kernel(const float* __restrict__ A, const float* __restrict__ BT,
                               const float* __restrict__ bias1, const float* __restrict__ bias2,
                               float* __restrict__ C) {
    constexpr int K4 = K / 4;
    __shared__ __align__(16) float s_a[64 * K];
    const int tid = threadIdx.x;
    const int m0 = blockIdx.x * 64;
    const int j0 = blockIdx.y * 128;

    const float4* Ag = (const float4*)A;
    for (int e = tid; e < 16 * K; e += 256) {
        int row = e / K4, c = e % K4;
        ((float4*)s_a)[row * K4 + (c ^ ((row >> 2) & 7))] = Ag[(size_t)(m0 + row) * K4 + c];
    }
    __syncthreads();

    const int ti = tid >> 4, tj = tid & 15;
    const int swz = ti & 7;
    const int j = j0 + tj * 8;
    const int jb = (j0 >> 2) + tj * 2;
    const float4* BT4 = (const float4*)BT;

    float4 accL[4], accH[4];
    #pragma unroll
    for (int ii = 0; ii < 4; ++ii) {
        accL[ii] = make_float4(0.f, 0.f, 0.f, 0.f);
        accH[ii] = make_float4(0.f, 0.f, 0.f, 0.f);
    }
    for (int c = 0; c < K4; ++c) {
        float4 a4[4];
        #pragma unroll
        for (int ii = 0; ii < 4; ++ii)
            a4[ii] = ((const float4*)s_a)[(4 * ti + ii) * K4 + (c ^ swz)];
        #pragma unroll
        for (int kk = 0; kk < 4; ++kk) {
            float4 b1 = BT4[(size_t)(c * 4 + kk) * 128 + jb];
            float4 b2 = BT4[(size_t)(c * 4 + kk) * 128 + jb + 1];
            #pragma unroll
            for (int ii = 0; ii < 4; ++ii) {
                float av = f4c(a4[ii], kk);
                fma4(accL[ii], av, b1);
                fma4(accH[ii], av, b2);
            }
        }
    }
    float4 bL = make_float4(bias1[j] + bias2[j], bias1[j + 1] + bias2[j + 1],
                            bias1[j + 2] + bias2[j + 2], bias1[j + 3] + bias2[j + 3]);
    float4 bH = make_float4(bias1[j + 4] + bias2[j + 4], bias1[j + 5] + bias2[j + 5],
                            bias1[j + 6] + bias2[j + 6], bias1[j + 7] + bias2[j + 7]);
    #pragma unroll
    for (int ii = 0; ii < 4; ++ii) {
        size_t row = (size_t)(m0 + 4 * ti + ii);
        float4 oL = make_float4(accL[ii].x + bL.x, accL[ii].y + bL.y,
                                accL[ii].z + bL.z, accL[ii].w + bL.w);
        float4 oH = make_float4(accH[ii].x + bH.x, accH[ii].y + bH.y,
                                accH[ii].z + bH.z, accH[ii].w + bH.w);
        ((float4*)C)[(row * 512 + j) >> 2] = oL;
        ((float4*)C)[(row * 512 + j + 4) >> 2] = oH;
    }
}

// ---------------------------------------------------------------------------
// LSTM recurrence v4: MFMA. 64 blocks x 512 thr (8 waves), 16 batch rows/block.
// Whh as persistent hi/lo bf16 B-frags in VGPRs; h bf16 in LDS (A-layout);
// xg fp32 exact (prefetched); c in registers; out0/classifier from exact fp32 h.
// ---------------------------------------------------------------------------
#define HS 136    // s_h row stride in shorts (68 dwords = 4 mod 32)
#define GS 516    // s_g2 row stride in floats (516 = 4 mod 32, 16B-mult)

template <bool FINAL>
__launch_bounds__(512)
__global__ void lstm_mfma(const float* __restrict__ xg, const short* __restrict__ whhfG,
                          float* __restrict__ out0,
                          const float* __restrict__ Wc1, const float* __restrict__ bc1,
                          const float* __restrict__ Wc2, const float* __restrict__ bc2,
                          float* __restrict__ out) {
    __shared__ __align__(16) short s_h[16 * HS];    // h bf16 [m][k]
    __shared__ __align__(16) float s_g2[16 * GS];   // mfma gates fp32 [m][n]
    __shared__ __align__(16) float s_hid[16 * 68];
    const int tid = threadIdx.x;
    const int w = tid >> 6, l = tid & 63, quad = l >> 4, l15 = l & 15;
    const int b0 = blockIdx.x * 16;
    const int u = tid & 127, r0 = tid >> 7;         // rows r0*4+j, unit u

    // persistent Whh fragments: wave w owns n-tiles NT = 4w..4w+3, 4 k-slices, hi/lo
    short8 whf[16], wlf[16];
    #pragma unroll
    for (int nt = 0; nt < 4; ++nt)
        #pragma unroll
        for (int ks = 0; ks < 4; ++ks) {
            size_t NT = (size_t)(w * 4 + nt);
            whf[nt * 4 + ks] = *(const short8*)(whhfG + (((NT * 4 + ks) * 2 + 0) * 64 + l) * 8);
            wlf[nt * 4 + ks] = *(const short8*)(whhfG + (((NT * 4 + ks) * 2 + 1) * 64 + l) * 8);
        }

    float c[4] = {0.f, 0.f, 0.f, 0.f};
    for (int e = tid; e < 16 * HS; e += 512) s_h[e] = 0;
    __syncthreads();

    for (int t = 0; t < 31; ++t) {
        // xg prefetch (issued before MFMA; consumed after barrier)
        float xgv[16];
        #pragma unroll
        for (int j = 0; j < 4; ++j) {
            size_t base = ((size_t)(b0 + r0 * 4 + j) * PNUM + t) * 512 + u;
            xgv[j * 4 + 0] = xg[base];
            xgv[j * 4 + 1] = xg[base + 128];
            xgv[j * 4 + 2] = xg[base + 256];
            xgv[j * 4 + 3] = xg[base + 384];
        }

        // gates_h = h @ Whh^T  (hi + lo)
        short8 af[4];
        #pragma unroll
        for (int ks = 0; ks < 4; ++ks)
            af[ks] = *(const short8*)&s_h[l15 * HS + ks * 32 + quad * 8];
        f32x4 z = {0.f, 0.f, 0.f, 0.f};
        f32x4 acc[4] = {z, z, z, z};
        #pragma unroll
        for (int nt = 0; nt < 4; ++nt)
            #pragma unroll
            for (int ks = 0; ks < 4; ++ks) {
                acc[nt] = MFMA16(af[ks], whf[nt * 4 + ks], acc[nt]);
                acc[nt] = MFMA16(af[ks], wlf[nt * 4 + ks], acc[nt]);
            }
        // D: lane holds rows m=quad*4+reg, col n = 64w + 16nt + l15 -> s_g2[m][n]
        #pragma unroll
        for (int nt = 0; nt < 4; ++nt) {
            int n = w * 64 + nt * 16 + l15;
            #pragma unroll
            for (int reg = 0; reg < 4; ++reg)
                s_g2[(quad * 4 + reg) * GS + n] = acc[nt][reg];   // 2-way banks, free
        }
        __syncthreads();

        // nonlinearity + state update (fp32 exact except h->bf16 for next MFMA)
        #pragma unroll
        for (int j = 0; j < 4; ++j) {
            int rr = r0 * 4 + j;
            float gi = xgv[j * 4 + 0] + s_g2[rr * GS + u];
            float gf = xgv[j * 4 + 1] + s_g2[rr * GS + 128 + u];
            float gg = xgv[j * 4 + 2] + s_g2[rr * GS + 256 + u];
            float go = xgv[j * 4 + 3] + s_g2[rr * GS + 384 + u];
            float cn = sigf(gf) * c[j] + sigf(gi) * tanhfast(gg);
            float h = sigf(go) * tanhfast(cn);
            c[j] = cn;
            s_h[rr * HS + u] = f2bf(h);
            if (!FINAL)
                out0[((size_t)(b0 + rr) * PNUM + t) * 128 + u] = h;
        }
        __syncthreads();
    }

    if (FINAL) {
        // classifier: hid = relu(h @ Wc1^T + bc1); out = hid @ Wc2^T + bc2
        #pragma unroll
        for (int it2 = 0; it2 < 2; ++it2) {
            int item = tid + it2 * 512;            // 0..1023 = 16 rows x 64 units
            int rr = item >> 6, uu = item & 63;
            float acc = bc1[uu];
            const float* wv = Wc1 + (size_t)uu * 128;
            #pragma unroll 8
            for (int k = 0; k < 128; ++k) acc += wv[k] * bf2f(s_h[rr * HS + k]);
            s_hid[rr * 68 + uu] = fmaxf(acc, 0.f);
        }
        __syncthreads();
        if (tid < 176) {
            int rr = tid / 11, cc = tid % 11;
            float acc = bc2[cc];
            #pragma unroll
            for (int uu = 0; uu < 64; ++uu) acc += Wc2[cc * 64 + uu] * s_hid[rr * 68 + uu];
            out[(size_t)(b0 + rr) * 11 + cc] = acc;
        }
    }
}

// ---------------------------------------------------------------------------
extern "C" void kernel_launch(void* const* d_in, const int* in_sizes, int n_in,
                              void* d_out, int out_size, void* d_ws, size_t ws_size,
                              hipStream_t stream) {
    (void)in_sizes; (void)n_in; (void)out_size; (void)ws_size;
    const float* I    = (const float*)d_in[0];
    const float* Q    = (const float*)d_in[1];
    const float* ew   = (const float*)d_in[2];
    const float* Wn1  = (const float*)d_in[3];
    const float* bn1  = (const float*)d_in[4];
    const float* Ws1  = (const float*)d_in[5];
    const float* bs1  = (const float*)d_in[6];
    const float* Wn2  = (const float*)d_in[7];
    const float* bn2  = (const float*)d_in[8];
    const float* Ws2  = (const float*)d_in[9];
    const float* bs2  = (const float*)d_in[10];
    const float* Wih0 = (const float*)d_in[11];
    const float* Whh0 = (const float*)d_in[12];
    const float* bih0 = (const float*)d_in[13];
    const float* bhh0 = (const float*)d_in[14];
    const float* Wih1 = (const float*)d_in[15];
    const float* Whh1 = (const float*)d_in[16];
    const float* bih1 = (const float*)d_in[17];
    const float* bhh1 = (const float*)d_in[18];
    const float* Wc1  = (const float*)d_in[19];
    const float* bc1  = (const float*)d_in[20];
    const float* Wc2  = (const float*)d_in[21];
    const float* bc2  = (const float*)d_in[22];
    float* out = (float*)d_out;

    // workspace (floats): ~90.4 MB
    float* wsp   = (float*)d_ws;
    float* adjn  = wsp;                           // 4096
    float* WihT0 = adjn  + 4096;                  // 32768
    float* WihT1 = WihT0 + 32768;                 // 65536
    short* adjfG  = (short*)(WihT1 + 65536);      // 3072 shorts
    short* wcatfG = adjfG + 3072;                 // 16384 shorts
    short* whhf0G = wcatfG + 16384;               // 131072 shorts
    short* whhf1G = whhf0G + 131072;              // 131072 shorts  (=> 140800 floats total)
    float* feats = WihT1 + 65536 + 140800;        // 2031616
    float* out0  = feats + 2031616;               // 4063232
    float* xg    = out0  + 4063232;               // 16252928 (shared by both layers)

    adj_kernel<<<1, 64, 0, stream>>>(ew, adjn);
    prep_kernel<<<522, 256, 0, stream>>>(Wih0, Whh0, Wih1, Whh1, adjn, Ws2, Wn2,
                                         WihT0, WihT1, adjfG, wcatfG, whhf0G, whhf1G);
    sage_mfma<<<512, 256, 0, stream>>>(I, Q, adjn, Wn1, bn1, Ws1, bs1,
                                       bn2, bs2, adjfG, wcatfG, feats);
    gemm512_kernel<64><<<dim3(496, 4), 256, 0, stream>>>(feats, WihT0, bih0, bhh0, xg);
    lstm_mfma<false><<<64, 512, 0, stream>>>(xg, whhf0G, out0,
                                             nullptr, nullptr, nullptr, nullptr, nullptr);
    gemm512_kernel<128><<<dim3(496, 4), 256, 0, stream>>>(out0, WihT1, bih1, bhh1, xg);
    lstm_mfma<true><<<64, 512, 0, stream>>>(xg, whhf1G, nullptr,
                                            Wc1, bc1, Wc2, bc2, out);
}

// Round 15
// 727.124 us; speedup vs baseline: 2.0103x; 1.0120x over previous
//
#include <hip/hip_runtime.h>
#include <hip/hip_bf16.h>
#include <math.h>

#define L_SZ 1024
#define STRIDE_ 32
#define WIN 8
#define PNUM 31

// LDS row strides (in shorts). dword strides = 36/68 = 4 mod 32 -> 2-way banks (free).
#define X1TS 72
#define CAS  136

typedef __attribute__((ext_vector_type(8))) short short8;
typedef __attribute__((ext_vector_type(4))) short short4v;
typedef __attribute__((ext_vector_type(4))) float f32x4;

#define MFMA16(a, b, c) __builtin_amdgcn_mfma_f32_16x16x32_bf16(a, b, c, 0, 0, 0)

__device__ __forceinline__ float sigf(float x) { return 1.0f / (1.0f + __expf(-x)); }
__device__ __forceinline__ float tanhfast(float x) {
    float ax = fabsf(x);
    float t = __expf(-2.0f * ax);
    return copysignf((1.0f - t) / (1.0f + t), x);
}
__device__ __forceinline__ short f2bf(float f) {
    __hip_bfloat16 h = __float2bfloat16(f);   // RNE
    return *reinterpret_cast<short*>(&h);
}
__device__ __forceinline__ float bf2f(short s) {
    __hip_bfloat16 h = *reinterpret_cast<__hip_bfloat16*>(&s);
    return __bfloat162float(h);
}
__device__ __forceinline__ float f4c(float4 v, int k) {
    return k == 0 ? v.x : (k == 1 ? v.y : (k == 2 ? v.z : v.w));
}
__device__ __forceinline__ void fma4(float4& acc, float s, float4 v) {
    acc.x += s * v.x; acc.y += s * v.y; acc.z += s * v.z; acc.w += s * v.w;
}

// ---------------------------------------------------------------------------
// adjn[i][j] = sigmoid(ew[i][j]) * mask(|i-j|<=8, i!=j) * deg_inv[i]
// ---------------------------------------------------------------------------
__global__ void adj_kernel(const float* __restrict__ ew, float* __restrict__ adjn) {
    int i = threadIdx.x;
    if (i >= 64) return;
    float sum = 0.f;
    for (int j = 0; j < 64; ++j) {
        int d = i - j; d = d < 0 ? -d : d;
        float a = (d <= WIN && d != 0) ? sigf(ew[i * 64 + j]) : 0.f;
        sum += a;
    }
    float dinv = (sum > 0.f) ? 1.0f / sum : 0.f;
    for (int j = 0; j < 64; ++j) {
        int d = i - j; d = d < 0 ? -d : d;
        float a = (d <= WIN && d != 0) ? sigf(ew[i * 64 + j]) : 0.f;
        adjn[i * 64 + j] = a * dinv;
    }
}

// ---------------------------------------------------------------------------
// prep:
//   blocks   0..127 : Wih0T [64][512]
//   blocks 128..383 : Wih1T [128][512]
//   blocks 384..393 : sage B-fragments (adj + wcat hi/lo)
//   blocks 394..457 : Whh0 MFMA B-fragments hi/lo (per-lane order)
//   blocks 458..521 : Whh1 MFMA B-fragments hi/lo
// ---------------------------------------------------------------------------
__global__ void prep_kernel(const float* __restrict__ Wih0, const float* __restrict__ Whh0,
                            const float* __restrict__ Wih1, const float* __restrict__ Whh1,
                            const float* __restrict__ adjn,
                            const float* __restrict__ Ws2, const float* __restrict__ Wn2,
                            float* __restrict__ Wih0T, float* __restrict__ Wih1T,
                            short* __restrict__ adjfG, short* __restrict__ wcatfG,
                            short* __restrict__ whhf0G, short* __restrict__ whhf1G) {
    int bid = blockIdx.x, tid = threadIdx.x;
    if (bid < 128) {                         // Wih0T [64][512] <- Wih0 [512][64]
        int e = bid * 256 + tid;
        int k = e >> 9, j = e & 511;
        Wih0T[e] = Wih0[j * 64 + k];
        return;
    }
    if (bid < 384) {                         // Wih1T [128][512] <- Wih1 [512][128]
        int e = (bid - 128) * 256 + tid;
        int k = e >> 9, j = e & 511;
        Wih1T[e] = Wih1[j * 128 + k];
        return;
    }
    if (bid < 394) {                         // sage fragments
        int t = (bid - 384) * 256 + tid;
        if (t >= 2432) return;
        int f = t >> 6, l = t & 63;
        int q = l >> 4, l15 = l & 15;
        short8 v;
        if (f < 6) {
            const int ntT[6] = {0, 1, 1, 2, 2, 3};
            const int ksT[6] = {0, 0, 1, 0, 1, 1};
            int row = l15 + 16 * ntT[f], col = 8 * q + 32 * ksT[f];
            #pragma unroll
            for (int e = 0; e < 8; ++e)
                v[e] = f2bf(adjn[row * 64 + col + e]);
            *(short8*)(adjfG + ((size_t)f * 64 + l) * 8) = v;
        } else {
            int fi = f - 6;
            int isLo = fi >= 16;
            int ff = isLo ? fi - 16 : fi;
            int nt = ff >> 2, ks = ff & 3;
            int oo = l15 + 16 * nt;
            #pragma unroll
            for (int e = 0; e < 8; ++e) {
                int k = 32 * ks + 8 * q + e;
                float src = (k < 64) ? Ws2[oo * 64 + k] : Wn2[oo * 64 + (k - 64)];
                short hi = f2bf(src);
                v[e] = isLo ? f2bf(src - bf2f(hi)) : hi;
            }
            *(short8*)(wcatfG + ((size_t)fi * 64 + l) * 8) = v;
        }
        return;
    }
    // Whh fragments: layer from block range; 16384 lane-frags per layer
    {
        int layer = (bid < 458) ? 0 : 1;
        int base = layer ? 458 : 394;
        const float* Whh = layer ? Whh1 : Whh0;
        short* dst = layer ? whhf1G : whhf0G;
        int t = (bid - base) * 256 + tid;    // 0..16383
        int frag = t >> 6, l = t & 63;
        int hl = frag & 1, ks = (frag >> 1) & 3, NT = frag >> 3;   // NT 0..31
        int g = NT * 16 + (l & 15);
        int kbase = ks * 32 + (l >> 4) * 8;
        short8 v;
        #pragma unroll
        for (int e = 0; e < 8; ++e) {
            float src = Whh[(size_t)g * 128 + kbase + e];
            short hi = f2bf(src);
            v[e] = hl ? f2bf(src - bf2f(hi)) : hi;
        }
        *(short8*)(dst + (size_t)t * 8) = v;
    }
}

// ---------------------------------------------------------------------------
// Persistent fused SAGE via bf16 MFMA: 1024 blocks x 31 patches.
// __launch_bounds__(256,2) UNCHANGED from R13 (same codegen, VGPR=128, no
// spill — R12 evidence: bounds change -> spill -> 2.5 GB scratch). The grid
// bump (512->1024) raises occupancy 2->4 blocks/CU: that was the real cap.
// Phase 1a merged into 1b (n0 recomputed per-thread, same j-order ->
// bit-identical); one fewer barrier + no s_n0 round-trip.
// ---------------------------------------------------------------------------
__launch_bounds__(256, 2)
__global__ void sage_mfma(const float* __restrict__ I, const float* __restrict__ Q,
                          const float* __restrict__ adjn,
                          const float* __restrict__ Wn1, const float* __restrict__ bn1,
                          const float* __restrict__ Ws1, const float* __restrict__ bs1,
                          const float* __restrict__ bn2, const float* __restrict__ bs2,
                          const short* __restrict__ adjfG, const short* __restrict__ wcatfG,
                          float* __restrict__ feats) {
    __shared__ __align__(16) short s_x1T[64 * X1TS];   // x1^T [o][i] bf16
    __shared__ __align__(16) short s_cat[64 * CAS];    // [i][0..63:x1, 64..127:n1] bf16
    __shared__ __align__(16) float s_x0[128];
    __shared__ __align__(16) float s_part[4][64];

    const int tid = threadIdx.x;
    const int w = tid >> 6, l = tid & 63, q = l >> 4, l15 = l & 15;

    short8 adjf[6];
    #pragma unroll
    for (int f = 0; f < 6; ++f)
        adjf[f] = *(const short8*)(adjfG + ((size_t)f * 64 + l) * 8);
    short8 whf[16], wlf[16];
    #pragma unroll
    for (int f = 0; f < 16; ++f) {
        whf[f] = *(const short8*)(wcatfG + ((size_t)f * 64 + l) * 8);
        wlf[f] = *(const short8*)(wcatfG + ((size_t)(f + 16) * 64 + l) * 8);
    }

    for (int it = 0; it < 31; ++it) {
        const int m = blockIdx.x + it * 1024;
        const int b = m / PNUM, p = m % PNUM;
        const float* Ibase = I + (size_t)b * L_SZ + p * STRIDE_;
        const float* Qbase = Q + (size_t)b * L_SZ + p * STRIDE_;

        if (tid < 128) {
            int i = tid >> 1, ch = tid & 1;
            s_x0[i * 2 + ch] = ch ? Qbase[i] : Ibase[i];
        }
        __syncthreads();

        // ---- Phase 1 (merged): n0 recomputed per-thread, x1 = relu(...) ----
        {
            int i = tid & 63, oc = tid >> 6;
            float x0a = s_x0[i * 2], x0b = s_x0[i * 2 + 1];
            int jlo = i - WIN; if (jlo < 0) jlo = 0;
            int jhi = i + WIN; if (jhi > 63) jhi = 63;
            float n0a = 0.f, n0b = 0.f;
            for (int j = jlo; j <= jhi; ++j) {       // same order as R13 phase 1a
                float a = adjn[i * 64 + j];          // L1-resident
                n0a += a * s_x0[j * 2];
                n0b += a * s_x0[j * 2 + 1];
            }
            union { short s[16]; short8 v[2]; } pk;
            #pragma unroll
            for (int t = 0; t < 16; ++t) {
                int o = oc * 16 + t;
                float2 wsv = ((const float2*)Ws1)[o];
                float2 wnv = ((const float2*)Wn1)[o];
                float v = bs1[o] + bn1[o] + wsv.x * x0a + wsv.y * x0b
                                          + wnv.x * n0a + wnv.y * n0b;
                v = fmaxf(v, 0.f);
                short bv = f2bf(v);
                s_x1T[o * X1TS + i] = bv;
                pk.s[t] = bv;
            }
            *(short8*)&s_cat[i * CAS + oc * 16]     = pk.v[0];
            *(short8*)&s_cat[i * CAS + oc * 16 + 8] = pk.v[1];
        }
        __syncthreads();

        {
            short8 a0 = *(const short8*)&s_x1T[(16 * w + l15) * X1TS + 8 * q];
            short8 a1 = *(const short8*)&s_x1T[(16 * w + l15) * X1TS + 8 * q + 32];
            f32x4 z = {0.f, 0.f, 0.f, 0.f};
            f32x4 c0 = z, c1 = z, c2 = z, c3 = z;
            c0 = MFMA16(a0, adjf[0], c0);
            c1 = MFMA16(a0, adjf[1], c1);
            c1 = MFMA16(a1, adjf[2], c1);
            c2 = MFMA16(a0, adjf[3], c2);
            c2 = MFMA16(a1, adjf[4], c2);
            c3 = MFMA16(a1, adjf[5], c3);
            f32x4 cc[4] = {c0, c1, c2, c3};
            #pragma unroll
            for (int nt = 0; nt < 4; ++nt) {
                short4v nv;
                nv[0] = f2bf(cc[nt][0]); nv[1] = f2bf(cc[nt][1]);
                nv[2] = f2bf(cc[nt][2]); nv[3] = f2bf(cc[nt][3]);
                *(short4v*)&s_cat[(l15 + 16 * nt) * CAS + 64 + 16 * w + 4 * q] = nv;
            }
        }
        __syncthreads();

        {
            short8 a2[4];
            #pragma unroll
            for (int ks = 0; ks < 4; ++ks)
                a2[ks] = *(const short8*)&s_cat[(16 * w + l15) * CAS + 32 * ks + 8 * q];
            f32x4 z = {0.f, 0.f, 0.f, 0.f};
            f32x4 acc2[4] = {z, z, z, z};
            #pragma unroll
            for (int nt = 0; nt < 4; ++nt) {
                #pragma unroll
                for (int ks = 0; ks < 4; ++ks) {
                    acc2[nt] = MFMA16(a2[ks], whf[nt * 4 + ks], acc2[nt]);
                    acc2[nt] = MFMA16(a2[ks], wlf[nt * 4 + ks], acc2[nt]);
                }
            }
            float part[4];
            #pragma unroll
            for (int nt = 0; nt < 4; ++nt) {
                int oo = l15 + 16 * nt;
                float bo = bs2[oo] + bn2[oo];
                float s = fmaxf(acc2[nt][0] + bo, 0.f) + fmaxf(acc2[nt][1] + bo, 0.f)
                        + fmaxf(acc2[nt][2] + bo, 0.f) + fmaxf(acc2[nt][3] + bo, 0.f);
                s += __shfl_xor(s, 16);
                s += __shfl_xor(s, 32);
                part[nt] = s;
            }
            if (l < 16) {
                #pragma unroll
                for (int nt = 0; nt < 4; ++nt)
                    s_part[w][l + 16 * nt] = part[nt];
            }
        }
        __syncthreads();
        if (tid < 64)
            feats[(size_t)m * 64 + tid] =
                s_part[0][tid] + s_part[1][tid] + s_part[2][tid] + s_part[3][tid];
    }
}

// ---------------------------------------------------------------------------
// GEMM: C[M x 512] = A[M x K] @ BT[K x 512] + bias1 + bias2  (verified)
// ---------------------------------------------------------------------------
template <int K>
__launch_bounds__(256, 2)
__global__ void gemm512_kernel(const float* __restrict__ A, const float* __restrict__ BT,
                               const float* __restrict__ bias1, const float* __restrict__ bias2,
                               float* __restrict__ C) {
    constexpr int K4 = K / 4;
    __shared__ __align__(16) float s_a[64 * K];
    const int tid = threadIdx.x;
    const int m0 = blockIdx.x * 64;
    const int j0 = blockIdx.y * 128;

    const float4* Ag = (const float4*)A;
    for (int e = tid; e < 16 * K; e += 256) {
        int row = e / K4, c = e % K4;
        ((float4*)s_a)[row * K4 + (c ^ ((row >> 2) & 7))] = Ag[(size_t)(m0 + row) * K4 + c];
    }
    __syncthreads();

    const int ti = tid >> 4, tj = tid & 15;
    const int swz = ti & 7;
    const int j = j0 + tj * 8;
    const int jb = (j0 >> 2) + tj * 2;
    const float4* BT4 = (const float4*)BT;

    float4 accL[4], accH[4];
    #pragma unroll
    for (int ii = 0; ii < 4; ++ii) {
        accL[ii] = make_float4(0.f, 0.f, 0.f, 0.f);
        accH[ii] = make_float4(0.f, 0.f, 0.f, 0.f);
    }
    for (int c = 0; c < K4; ++c) {
        float4 a4[4];
        #pragma unroll
        for (int ii = 0; ii < 4; ++ii)
            a4[ii] = ((const float4*)s_a)[(4 * ti + ii) * K4 + (c ^ swz)];
        #pragma unroll
        for (int kk = 0; kk < 4; ++kk) {
            float4 b1 = BT4[(size_t)(c * 4 + kk) * 128 + jb];
            float4 b2 = BT4[(size_t)(c * 4 + kk) * 128 + jb + 1];
            #pragma unroll
            for (int ii = 0; ii < 4; ++ii) {
                float av = f4c(a4[ii], kk);
                fma4(accL[ii], av, b1);
                fma4(accH[ii], av, b2);
            }
        }
    }
    float4 bL = make_float4(bias1[j] + bias2[j], bias1[j + 1] + bias2[j + 1],
                            bias1[j + 2] + bias2[j + 2], bias1[j + 3] + bias2[j + 3]);
    float4 bH = make_float4(bias1[j + 4] + bias2[j + 4], bias1[j + 5] + bias2[j + 5],
                            bias1[j + 6] + bias2[j + 6], bias1[j + 7] + bias2[j + 7]);
    #pragma unroll
    for (int ii = 0; ii < 4; ++ii) {
        size_t row = (size_t)(m0 + 4 * ti + ii);
        float4 oL = make_float4(accL[ii].x + bL.x, accL[ii].y + bL.y,
                                accL[ii].z + bL.z, accL[ii].w + bL.w);
        float4 oH = make_float4(accH[ii].x + bH.x, accH[ii].y + bH.y,
                                accH[ii].z + bH.z, accH[ii].w + bH.w);
        ((float4*)C)[(row * 512 + j) >> 2] = oL;
        ((float4*)C)[(row * 512 + j + 4) >> 2] = oH;
    }
}

// ---------------------------------------------------------------------------
// LSTM recurrence v4: MFMA. 64 blocks x 512 thr (8 waves), 16 batch rows/block.
// (unchanged from R14)
// ---------------------------------------------------------------------------
#define HS 136    // s_h row stride in shorts (68 dwords = 4 mod 32)
#define GS 516    // s_g2 row stride in floats (516 = 4 mod 32, 16B-mult)

template <bool FINAL>
__launch_bounds__(512)
__global__ void lstm_mfma(const float* __restrict__ xg, const short* __restrict__ whhfG,
                          float* __restrict__ out0,
                          const float* __restrict__ Wc1, const float* __restrict__ bc1,
                          const float* __restrict__ Wc2, const float* __restrict__ bc2,
                          float* __restrict__ out) {
    __shared__ __align__(16) short s_h[16 * HS];    // h bf16 [m][k]
    __shared__ __align__(16) float s_g2[16 * GS];   // mfma gates fp32 [m][n]
    __shared__ __align__(16) float s_hid[16 * 68];
    const int tid = threadIdx.x;
    const int w = tid >> 6, l = tid & 63, quad = l >> 4, l15 = l & 15;
    const int b0 = blockIdx.x * 16;
    const int u = tid & 127, r0 = tid >> 7;         // rows r0*4+j, unit u

    short8 whf[16], wlf[16];
    #pragma unroll
    for (int nt = 0; nt < 4; ++nt)
        #pragma unroll
        for (int ks = 0; ks < 4; ++ks) {
            size_t NT = (size_t)(w * 4 + nt);
            whf[nt * 4 + ks] = *(const short8*)(whhfG + (((NT * 4 + ks) * 2 + 0) * 64 + l) * 8);
            wlf[nt * 4 + ks] = *(const short8*)(whhfG + (((NT * 4 + ks) * 2 + 1) * 64 + l) * 8);
        }

    float c[4] = {0.f, 0.f, 0.f, 0.f};
    for (int e = tid; e < 16 * HS; e += 512) s_h[e] = 0;
    __syncthreads();

    for (int t = 0; t < 31; ++t) {
        float xgv[16];
        #pragma unroll
        for (int j = 0; j < 4; ++j) {
            size_t base = ((size_t)(b0 + r0 * 4 + j) * PNUM + t) * 512 + u;
            xgv[j * 4 + 0] = xg[base];
            xgv[j * 4 + 1] = xg[base + 128];
            xgv[j * 4 + 2] = xg[base + 256];
            xgv[j * 4 + 3] = xg[base + 384];
        }

        short8 af[4];
        #pragma unroll
        for (int ks = 0; ks < 4; ++ks)
            af[ks] = *(const short8*)&s_h[l15 * HS + ks * 32 + quad * 8];
        f32x4 z = {0.f, 0.f, 0.f, 0.f};
        f32x4 acc[4] = {z, z, z, z};
        #pragma unroll
        for (int nt = 0; nt < 4; ++nt)
            #pragma unroll
            for (int ks = 0; ks < 4; ++ks) {
                acc[nt] = MFMA16(af[ks], whf[nt * 4 + ks], acc[nt]);
                acc[nt] = MFMA16(af[ks], wlf[nt * 4 + ks], acc[nt]);
            }
        #pragma unroll
        for (int nt = 0; nt < 4; ++nt) {
            int n = w * 64 + nt * 16 + l15;
            #pragma unroll
            for (int reg = 0; reg < 4; ++reg)
                s_g2[(quad * 4 + reg) * GS + n] = acc[nt][reg];
        }
        __syncthreads();

        #pragma unroll
        for (int j = 0; j < 4; ++j) {
            int rr = r0 * 4 + j;
            float gi = xgv[j * 4 + 0] + s_g2[rr * GS + u];
            float gf = xgv[j * 4 + 1] + s_g2[rr * GS + 128 + u];
            float gg = xgv[j * 4 + 2] + s_g2[rr * GS + 256 + u];
            float go = xgv[j * 4 + 3] + s_g2[rr * GS + 384 + u];
            float cn = sigf(gf) * c[j] + sigf(gi) * tanhfast(gg);
            float h = sigf(go) * tanhfast(cn);
            c[j] = cn;
            s_h[rr * HS + u] = f2bf(h);
            if (!FINAL)
                out0[((size_t)(b0 + rr) * PNUM + t) * 128 + u] = h;
        }
        __syncthreads();
    }

    if (FINAL) {
        #pragma unroll
        for (int it2 = 0; it2 < 2; ++it2) {
            int item = tid + it2 * 512;
            int rr = item >> 6, uu = item & 63;
            float acc = bc1[uu];
            const float* wv = Wc1 + (size_t)uu * 128;
            #pragma unroll 8
            for (int k = 0; k < 128; ++k) acc += wv[k] * bf2f(s_h[rr * HS + k]);
            s_hid[rr * 68 + uu] = fmaxf(acc, 0.f);
        }
        __syncthreads();
        if (tid < 176) {
            int rr = tid / 11, cc = tid % 11;
            float acc = bc2[cc];
            #pragma unroll
            for (int uu = 0; uu < 64; ++uu) acc += Wc2[cc * 64 + uu] * s_hid[rr * 68 + uu];
            out[(size_t)(b0 + rr) * 11 + cc] = acc;
        }
    }
}

// ---------------------------------------------------------------------------
extern "C" void kernel_launch(void* const* d_in, const int* in_sizes, int n_in,
                              void* d_out, int out_size, void* d_ws, size_t ws_size,
                              hipStream_t stream) {
    (void)in_sizes; (void)n_in; (void)out_size; (void)ws_size;
    const float* I    = (const float*)d_in[0];
    const float* Q    = (const float*)d_in[1];
    const float* ew   = (const float*)d_in[2];
    const float* Wn1  = (const float*)d_in[3];
    const float* bn1  = (const float*)d_in[4];
    const float* Ws1  = (const float*)d_in[5];
    const float* bs1  = (const float*)d_in[6];
    const float* Wn2  = (const float*)d_in[7];
    const float* bn2  = (const float*)d_in[8];
    const float* Ws2  = (const float*)d_in[9];
    const float* bs2  = (const float*)d_in[10];
    const float* Wih0 = (const float*)d_in[11];
    const float* Whh0 = (const float*)d_in[12];
    const float* bih0 = (const float*)d_in[13];
    const float* bhh0 = (const float*)d_in[14];
    const float* Wih1 = (const float*)d_in[15];
    const float* Whh1 = (const float*)d_in[16];
    const float* bih1 = (const float*)d_in[17];
    const float* bhh1 = (const float*)d_in[18];
    const float* Wc1  = (const float*)d_in[19];
    const float* bc1  = (const float*)d_in[20];
    const float* Wc2  = (const float*)d_in[21];
    const float* bc2  = (const float*)d_in[22];
    float* out = (float*)d_out;

    // workspace (floats): ~90.4 MB
    float* wsp   = (float*)d_ws;
    float* adjn  = wsp;                           // 4096
    float* WihT0 = adjn  + 4096;                  // 32768
    float* WihT1 = WihT0 + 32768;                 // 65536
    short* adjfG  = (short*)(WihT1 + 65536);      // 3072 shorts
    short* wcatfG = adjfG + 3072;                 // 16384 shorts
    short* whhf0G = wcatfG + 16384;               // 131072 shorts
    short* whhf1G = whhf0G + 131072;              // 131072 shorts  (=> 140800 floats total)
    float* feats = WihT1 + 65536 + 140800;        // 2031616
    float* out0  = feats + 2031616;               // 4063232
    float* xg    = out0  + 4063232;               // 16252928 (shared by both layers)

    adj_kernel<<<1, 64, 0, stream>>>(ew, adjn);
    prep_kernel<<<522, 256, 0, stream>>>(Wih0, Whh0, Wih1, Whh1, adjn, Ws2, Wn2,
                                         WihT0, WihT1, adjfG, wcatfG, whhf0G, whhf1G);
    sage_mfma<<<1024, 256, 0, stream>>>(I, Q, adjn, Wn1, bn1, Ws1, bs1,
                                        bn2, bs2, adjfG, wcatfG, feats);
    gemm512_kernel<64><<<dim3(496, 4), 256, 0, stream>>>(feats, WihT0, bih0, bhh0, xg);
    lstm_mfma<false><<<64, 512, 0, stream>>>(xg, whhf0G, out0,
                                             nullptr, nullptr, nullptr, nullptr, nullptr);
    gemm512_kernel<128><<<dim3(496, 4), 256, 0, stream>>>(out0, WihT1, bih1, bhh1, xg);
    lstm_mfma<true><<<64, 512, 0, stream>>>(xg, whhf1G, nullptr,
                                            Wc1, bc1, Wc2, bc2, out);
}

// Round 16
// 693.333 us; speedup vs baseline: 2.1082x; 1.0487x over previous
//
#include <hip/hip_runtime.h>
#include <hip/hip_bf16.h>
#include <math.h>

#define L_SZ 1024
#define STRIDE_ 32
#define WIN 8
#define PNUM 31

// LDS row strides (in shorts). dword strides = 36/68 = 4 mod 32 -> 2-way banks (free).
#define X1TS 72
#define CAS  136

typedef __attribute__((ext_vector_type(8))) short short8;
typedef __attribute__((ext_vector_type(4))) short short4v;
typedef __attribute__((ext_vector_type(4))) float f32x4;

#define MFMA16(a, b, c) __builtin_amdgcn_mfma_f32_16x16x32_bf16(a, b, c, 0, 0, 0)

__device__ __forceinline__ float sigf(float x) { return 1.0f / (1.0f + __expf(-x)); }
__device__ __forceinline__ float tanhfast(float x) {
    float ax = fabsf(x);
    float t = __expf(-2.0f * ax);
    return copysignf((1.0f - t) / (1.0f + t), x);
}
__device__ __forceinline__ short f2bf(float f) {
    __hip_bfloat16 h = __float2bfloat16(f);   // RNE
    return *reinterpret_cast<short*>(&h);
}
__device__ __forceinline__ float bf2f(short s) {
    __hip_bfloat16 h = *reinterpret_cast<__hip_bfloat16*>(&s);
    return __bfloat162float(h);
}
__device__ __forceinline__ float f4c(float4 v, int k) {
    return k == 0 ? v.x : (k == 1 ? v.y : (k == 2 ? v.z : v.w));
}
__device__ __forceinline__ void fma4(float4& acc, float s, float4 v) {
    acc.x += s * v.x; acc.y += s * v.y; acc.z += s * v.z; acc.w += s * v.w;
}

// ---------------------------------------------------------------------------
// adjn[i][j] = sigmoid(ew[i][j]) * mask(|i-j|<=8, i!=j) * deg_inv[i]
// ---------------------------------------------------------------------------
__global__ void adj_kernel(const float* __restrict__ ew, float* __restrict__ adjn) {
    int i = threadIdx.x;
    if (i >= 64) return;
    float sum = 0.f;
    for (int j = 0; j < 64; ++j) {
        int d = i - j; d = d < 0 ? -d : d;
        float a = (d <= WIN && d != 0) ? sigf(ew[i * 64 + j]) : 0.f;
        sum += a;
    }
    float dinv = (sum > 0.f) ? 1.0f / sum : 0.f;
    for (int j = 0; j < 64; ++j) {
        int d = i - j; d = d < 0 ? -d : d;
        float a = (d <= WIN && d != 0) ? sigf(ew[i * 64 + j]) : 0.f;
        adjn[i * 64 + j] = a * dinv;
    }
}

// ---------------------------------------------------------------------------
// prep (unchanged from R15):
//   blocks   0..127 : Wih0T | 128..383 : Wih1T | 384..393 : sage frags
//   blocks 394..457 : Whh0 frags hi/lo | 458..521 : Whh1 frags hi/lo
// ---------------------------------------------------------------------------
__global__ void prep_kernel(const float* __restrict__ Wih0, const float* __restrict__ Whh0,
                            const float* __restrict__ Wih1, const float* __restrict__ Whh1,
                            const float* __restrict__ adjn,
                            const float* __restrict__ Ws2, const float* __restrict__ Wn2,
                            float* __restrict__ Wih0T, float* __restrict__ Wih1T,
                            short* __restrict__ adjfG, short* __restrict__ wcatfG,
                            short* __restrict__ whhf0G, short* __restrict__ whhf1G) {
    int bid = blockIdx.x, tid = threadIdx.x;
    if (bid < 128) {
        int e = bid * 256 + tid;
        int k = e >> 9, j = e & 511;
        Wih0T[e] = Wih0[j * 64 + k];
        return;
    }
    if (bid < 384) {
        int e = (bid - 128) * 256 + tid;
        int k = e >> 9, j = e & 511;
        Wih1T[e] = Wih1[j * 128 + k];
        return;
    }
    if (bid < 394) {
        int t = (bid - 384) * 256 + tid;
        if (t >= 2432) return;
        int f = t >> 6, l = t & 63;
        int q = l >> 4, l15 = l & 15;
        short8 v;
        if (f < 6) {
            const int ntT[6] = {0, 1, 1, 2, 2, 3};
            const int ksT[6] = {0, 0, 1, 0, 1, 1};
            int row = l15 + 16 * ntT[f], col = 8 * q + 32 * ksT[f];
            #pragma unroll
            for (int e = 0; e < 8; ++e)
                v[e] = f2bf(adjn[row * 64 + col + e]);
            *(short8*)(adjfG + ((size_t)f * 64 + l) * 8) = v;
        } else {
            int fi = f - 6;
            int isLo = fi >= 16;
            int ff = isLo ? fi - 16 : fi;
            int nt = ff >> 2, ks = ff & 3;
            int oo = l15 + 16 * nt;
            #pragma unroll
            for (int e = 0; e < 8; ++e) {
                int k = 32 * ks + 8 * q + e;
                float src = (k < 64) ? Ws2[oo * 64 + k] : Wn2[oo * 64 + (k - 64)];
                short hi = f2bf(src);
                v[e] = isLo ? f2bf(src - bf2f(hi)) : hi;
            }
            *(short8*)(wcatfG + ((size_t)fi * 64 + l) * 8) = v;
        }
        return;
    }
    {
        int layer = (bid < 458) ? 0 : 1;
        int base = layer ? 458 : 394;
        const float* Whh = layer ? Whh1 : Whh0;
        short* dst = layer ? whhf1G : whhf0G;
        int t = (bid - base) * 256 + tid;    // 0..16383
        int frag = t >> 6, l = t & 63;
        int hl = frag & 1, ks = (frag >> 1) & 3, NT = frag >> 3;
        int g = NT * 16 + (l & 15);
        int kbase = ks * 32 + (l >> 4) * 8;
        short8 v;
        #pragma unroll
        for (int e = 0; e < 8; ++e) {
            float src = Whh[(size_t)g * 128 + kbase + e];
            short hi = f2bf(src);
            v[e] = hl ? f2bf(src - bf2f(hi)) : hi;
        }
        *(short8*)(dst + (size_t)t * 8) = v;
    }
}

// ---------------------------------------------------------------------------
// Persistent fused SAGE, bf16 MFMA. 512 blocks x 31 iters x 2 patches/iter.
// Register-limited to 2 blocks/CU (R15 evidence: grid bump flat) -> amortize
// barriers: (a) MFMA#1 re-tiled wave-local (wave w computes n1 for ITS i-tile;
// producer==consumer -> no barrier before MFMA#2); (b) 2 patches share the 3
// remaining barriers. Per-element math & accumulation order bit-identical.
// __launch_bounds__(256,2) unchanged (R12: changing it causes spill).
// ---------------------------------------------------------------------------
__launch_bounds__(256, 2)
__global__ void sage_mfma(const float* __restrict__ I, const float* __restrict__ Q,
                          const float* __restrict__ adjn,
                          const float* __restrict__ Wn1, const float* __restrict__ bn1,
                          const float* __restrict__ Ws1, const float* __restrict__ bs1,
                          const float* __restrict__ bn2, const float* __restrict__ bs2,
                          const short* __restrict__ adjfG, const short* __restrict__ wcatfG,
                          float* __restrict__ feats) {
    __shared__ __align__(16) short s_x1T[2][64 * X1TS];  // x1^T [o][i] bf16
    __shared__ __align__(16) short s_cat[2][64 * CAS];   // [i][x1|n1] bf16
    __shared__ __align__(16) float s_x0[2][128];
    __shared__ __align__(16) float s_part[2][4][64];

    const int tid = threadIdx.x;
    const int w = tid >> 6, l = tid & 63, q = l >> 4, l15 = l & 15;

    // adj frags for THIS wave's i-tile (band): w0:{ks0}, w1/w2:{ks0,ks1}, w3:{ks1}
    const bool hasKs0 = (w <= 2);
    const bool hasKs1 = (w >= 1);
    const int idx0 = (w == 0) ? 0 : (w == 1 ? 1 : 3);    // frag idx for (nt=w, ks=0)
    const int idx1 = (w == 1) ? 2 : (w == 2 ? 4 : 5);    // frag idx for (nt=w, ks=1)
    short8 adjB0 = {}, adjB1 = {};
    if (hasKs0) adjB0 = *(const short8*)(adjfG + ((size_t)idx0 * 64 + l) * 8);
    if (hasKs1) adjB1 = *(const short8*)(adjfG + ((size_t)idx1 * 64 + l) * 8);

    short8 whf[16], wlf[16];
    #pragma unroll
    for (int f = 0; f < 16; ++f) {
        whf[f] = *(const short8*)(wcatfG + ((size_t)f * 64 + l) * 8);
        wlf[f] = *(const short8*)(wcatfG + ((size_t)(f + 16) * 64 + l) * 8);
    }

    for (int it = 0; it < 31; ++it) {
        const int mbase = it * 1024 + blockIdx.x;        // mA; mB = mA + 512

        // ---- stage x0 for both patches ----
        {
            int P = tid >> 7, t2 = tid & 127;
            int i = t2 >> 1, ch = t2 & 1;
            int m = mbase + P * 512;
            int b = m / PNUM, p = m % PNUM;
            const float* base = (ch ? Q : I) + (size_t)b * L_SZ + p * STRIDE_;
            s_x0[P][i * 2 + ch] = base[i];
        }
        __syncthreads();

        // ---- Phase 1 (both patches): n0 per-thread, x1 = relu(...) ----
        #pragma unroll
        for (int P = 0; P < 2; ++P) {
            int i = tid & 63, oc = tid >> 6;
            float x0a = s_x0[P][i * 2], x0b = s_x0[P][i * 2 + 1];
            int jlo = i - WIN; if (jlo < 0) jlo = 0;
            int jhi = i + WIN; if (jhi > 63) jhi = 63;
            float n0a = 0.f, n0b = 0.f;
            for (int j = jlo; j <= jhi; ++j) {           // same j-order: bit-identical
                float a = adjn[i * 64 + j];              // L1-resident
                n0a += a * s_x0[P][j * 2];
                n0b += a * s_x0[P][j * 2 + 1];
            }
            union { short s[16]; short8 v[2]; } pk;
            #pragma unroll
            for (int t = 0; t < 16; ++t) {
                int o = oc * 16 + t;
                float2 wsv = ((const float2*)Ws1)[o];
                float2 wnv = ((const float2*)Wn1)[o];
                float v = bs1[o] + bn1[o] + wsv.x * x0a + wsv.y * x0b
                                          + wnv.x * n0a + wnv.y * n0b;
                v = fmaxf(v, 0.f);
                short bv = f2bf(v);
                s_x1T[P][o * X1TS + i] = bv;
                pk.s[t] = bv;
            }
            *(short8*)&s_cat[P][i * CAS + oc * 16]     = pk.v[0];
            *(short8*)&s_cat[P][i * CAS + oc * 16 + 8] = pk.v[1];
        }
        __syncthreads();

        // ---- per patch: MFMA#1 (wave-local i-tile) then MFMA#2, no barrier ----
        #pragma unroll
        for (int P = 0; P < 2; ++P) {
            // MFMA#1: n1^T for i-tile w. A = x1T o-tiles, B = adj (this wave's cols).
            #pragma unroll
            for (int ot = 0; ot < 4; ++ot) {
                f32x4 c = {0.f, 0.f, 0.f, 0.f};
                if (hasKs0) {
                    short8 a = *(const short8*)&s_x1T[P][(16 * ot + l15) * X1TS + 8 * q];
                    c = MFMA16(a, adjB0, c);
                }
                if (hasKs1) {
                    short8 a = *(const short8*)&s_x1T[P][(16 * ot + l15) * X1TS + 8 * q + 32];
                    c = MFMA16(a, adjB1, c);
                }
                // C: col i = 16w+l15 (lane), rows o = 16ot+4q+reg -> b64 write
                short4v nv;
                nv[0] = f2bf(c[0]); nv[1] = f2bf(c[1]);
                nv[2] = f2bf(c[2]); nv[3] = f2bf(c[3]);
                *(short4v*)&s_cat[P][(16 * w + l15) * CAS + 64 + 16 * ot + 4 * q] = nv;
            }
            // MFMA#2: same-wave rows; lgkmcnt (compiler) orders the n1 RAW.
            short8 a2[4];
            #pragma unroll
            for (int ks = 0; ks < 4; ++ks)
                a2[ks] = *(const short8*)&s_cat[P][(16 * w + l15) * CAS + 32 * ks + 8 * q];
            f32x4 z = {0.f, 0.f, 0.f, 0.f};
            f32x4 acc2[4] = {z, z, z, z};
            #pragma unroll
            for (int nt = 0; nt < 4; ++nt) {
                #pragma unroll
                for (int ks = 0; ks < 4; ++ks) {
                    acc2[nt] = MFMA16(a2[ks], whf[nt * 4 + ks], acc2[nt]);
                    acc2[nt] = MFMA16(a2[ks], wlf[nt * 4 + ks], acc2[nt]);
                }
            }
            float part[4];
            #pragma unroll
            for (int nt = 0; nt < 4; ++nt) {
                int oo = l15 + 16 * nt;
                float bo = bs2[oo] + bn2[oo];
                float s = fmaxf(acc2[nt][0] + bo, 0.f) + fmaxf(acc2[nt][1] + bo, 0.f)
                        + fmaxf(acc2[nt][2] + bo, 0.f) + fmaxf(acc2[nt][3] + bo, 0.f);
                s += __shfl_xor(s, 16);
                s += __shfl_xor(s, 32);
                part[nt] = s;
            }
            if (l < 16) {
                #pragma unroll
                for (int nt = 0; nt < 4; ++nt)
                    s_part[P][w][l + 16 * nt] = part[nt];
            }
        }
        __syncthreads();
        if (tid < 128) {
            int P = tid >> 6, i = tid & 63;
            int m = mbase + P * 512;
            feats[(size_t)m * 64 + i] = s_part[P][0][i] + s_part[P][1][i]
                                      + s_part[P][2][i] + s_part[P][3][i];
        }
    }
}

// ---------------------------------------------------------------------------
// GEMM: C[M x 512] = A[M x K] @ BT[K x 512] + bias1 + bias2  (verified)
// ---------------------------------------------------------------------------
template <int K>
__launch_bounds__(256, 2)
__global__ void gemm512_kernel(const float* __restrict__ A, const float* __restrict__ BT,
                               const float* __restrict__ bias1, const float* __restrict__ bias2,
                               float* __restrict__ C) {
    constexpr int K4 = K / 4;
    __shared__ __align__(16) float s_a[64 * K];
    const int tid = threadIdx.x;
    const int m0 = blockIdx.x * 64;
    const int j0 = blockIdx.y * 128;

    const float4* Ag = (const float4*)A;
    for (int e = tid; e < 16 * K; e += 256) {
        int row = e / K4, c = e % K4;
        ((float4*)s_a)[row * K4 + (c ^ ((row >> 2) & 7))] = Ag[(size_t)(m0 + row) * K4 + c];
    }
    __syncthreads();

    const int ti = tid >> 4, tj = tid & 15;
    const int swz = ti & 7;
    const int j = j0 + tj * 8;
    const int jb = (j0 >> 2) + tj * 2;
    const float4* BT4 = (const float4*)BT;

    float4 accL[4], accH[4];
    #pragma unroll
    for (int ii = 0; ii < 4; ++ii) {
        accL[ii] = make_float4(0.f, 0.f, 0.f, 0.f);
        accH[ii] = make_float4(0.f, 0.f, 0.f, 0.f);
    }
    for (int c = 0; c < K4; ++c) {
        float4 a4[4];
        #pragma unroll
        for (int ii = 0; ii < 4; ++ii)
            a4[ii] = ((const float4*)s_a)[(4 * ti + ii) * K4 + (c ^ swz)];
        #pragma unroll
        for (int kk = 0; kk < 4; ++kk) {
            float4 b1 = BT4[(size_t)(c * 4 + kk) * 128 + jb];
            float4 b2 = BT4[(size_t)(c * 4 + kk) * 128 + jb + 1];
            #pragma unroll
            for (int ii = 0; ii < 4; ++ii) {
                float av = f4c(a4[ii], kk);
                fma4(accL[ii], av, b1);
                fma4(accH[ii], av, b2);
            }
        }
    }
    float4 bL = make_float4(bias1[j] + bias2[j], bias1[j + 1] + bias2[j + 1],
                            bias1[j + 2] + bias2[j + 2], bias1[j + 3] + bias2[j + 3]);
    float4 bH = make_float4(bias1[j + 4] + bias2[j + 4], bias1[j + 5] + bias2[j + 5],
                            bias1[j + 6] + bias2[j + 6], bias1[j + 7] + bias2[j + 7]);
    #pragma unroll
    for (int ii = 0; ii < 4; ++ii) {
        size_t row = (size_t)(m0 + 4 * ti + ii);
        float4 oL = make_float4(accL[ii].x + bL.x, accL[ii].y + bL.y,
                                accL[ii].z + bL.z, accL[ii].w + bL.w);
        float4 oH = make_float4(accH[ii].x + bH.x, accH[ii].y + bH.y,
                                accH[ii].z + bH.z, accH[ii].w + bH.w);
        ((float4*)C)[(row * 512 + j) >> 2] = oL;
        ((float4*)C)[(row * 512 + j + 4) >> 2] = oH;
    }
}

// ---------------------------------------------------------------------------
// LSTM recurrence v4: MFMA (unchanged from R14/R15).
// ---------------------------------------------------------------------------
#define HS 136    // s_h row stride in shorts (68 dwords = 4 mod 32)
#define GS 516    // s_g2 row stride in floats (516 = 4 mod 32, 16B-mult)

template <bool FINAL>
__launch_bounds__(512)
__global__ void lstm_mfma(const float* __restrict__ xg, const short* __restrict__ whhfG,
                          float* __restrict__ out0,
                          const float* __restrict__ Wc1, const float* __restrict__ bc1,
                          const float* __restrict__ Wc2, const float* __restrict__ bc2,
                          float* __restrict__ out) {
    __shared__ __align__(16) short s_h[16 * HS];    // h bf16 [m][k]
    __shared__ __align__(16) float s_g2[16 * GS];   // mfma gates fp32 [m][n]
    __shared__ __align__(16) float s_hid[16 * 68];
    const int tid = threadIdx.x;
    const int w = tid >> 6, l = tid & 63, quad = l >> 4, l15 = l & 15;
    const int b0 = blockIdx.x * 16;
    const int u = tid & 127, r0 = tid >> 7;

    short8 whf[16], wlf[16];
    #pragma unroll
    for (int nt = 0; nt < 4; ++nt)
        #pragma unroll
        for (int ks = 0; ks < 4; ++ks) {
            size_t NT = (size_t)(w * 4 + nt);
            whf[nt * 4 + ks] = *(const short8*)(whhfG + (((NT * 4 + ks) * 2 + 0) * 64 + l) * 8);
            wlf[nt * 4 + ks] = *(const short8*)(whhfG + (((NT * 4 + ks) * 2 + 1) * 64 + l) * 8);
        }

    float c[4] = {0.f, 0.f, 0.f, 0.f};
    for (int e = tid; e < 16 * HS; e += 512) s_h[e] = 0;
    __syncthreads();

    for (int t = 0; t < 31; ++t) {
        float xgv[16];
        #pragma unroll
        for (int j = 0; j < 4; ++j) {
            size_t base = ((size_t)(b0 + r0 * 4 + j) * PNUM + t) * 512 + u;
            xgv[j * 4 + 0] = xg[base];
            xgv[j * 4 + 1] = xg[base + 128];
            xgv[j * 4 + 2] = xg[base + 256];
            xgv[j * 4 + 3] = xg[base + 384];
        }

        short8 af[4];
        #pragma unroll
        for (int ks = 0; ks < 4; ++ks)
            af[ks] = *(const short8*)&s_h[l15 * HS + ks * 32 + quad * 8];
        f32x4 z = {0.f, 0.f, 0.f, 0.f};
        f32x4 acc[4] = {z, z, z, z};
        #pragma unroll
        for (int nt = 0; nt < 4; ++nt)
            #pragma unroll
            for (int ks = 0; ks < 4; ++ks) {
                acc[nt] = MFMA16(af[ks], whf[nt * 4 + ks], acc[nt]);
                acc[nt] = MFMA16(af[ks], wlf[nt * 4 + ks], acc[nt]);
            }
        #pragma unroll
        for (int nt = 0; nt < 4; ++nt) {
            int n = w * 64 + nt * 16 + l15;
            #pragma unroll
            for (int reg = 0; reg < 4; ++reg)
                s_g2[(quad * 4 + reg) * GS + n] = acc[nt][reg];
        }
        __syncthreads();

        #pragma unroll
        for (int j = 0; j < 4; ++j) {
            int rr = r0 * 4 + j;
            float gi = xgv[j * 4 + 0] + s_g2[rr * GS + u];
            float gf = xgv[j * 4 + 1] + s_g2[rr * GS + 128 + u];
            float gg = xgv[j * 4 + 2] + s_g2[rr * GS + 256 + u];
            float go = xgv[j * 4 + 3] + s_g2[rr * GS + 384 + u];
            float cn = sigf(gf) * c[j] + sigf(gi) * tanhfast(gg);
            float h = sigf(go) * tanhfast(cn);
            c[j] = cn;
            s_h[rr * HS + u] = f2bf(h);
            if (!FINAL)
                out0[((size_t)(b0 + rr) * PNUM + t) * 128 + u] = h;
        }
        __syncthreads();
    }

    if (FINAL) {
        #pragma unroll
        for (int it2 = 0; it2 < 2; ++it2) {
            int item = tid + it2 * 512;
            int rr = item >> 6, uu = item & 63;
            float acc = bc1[uu];
            const float* wv = Wc1 + (size_t)uu * 128;
            #pragma unroll 8
            for (int k = 0; k < 128; ++k) acc += wv[k] * bf2f(s_h[rr * HS + k]);
            s_hid[rr * 68 + uu] = fmaxf(acc, 0.f);
        }
        __syncthreads();
        if (tid < 176) {
            int rr = tid / 11, cc = tid % 11;
            float acc = bc2[cc];
            #pragma unroll
            for (int uu = 0; uu < 64; ++uu) acc += Wc2[cc * 64 + uu] * s_hid[rr * 68 + uu];
            out[(size_t)(b0 + rr) * 11 + cc] = acc;
        }
    }
}

// ---------------------------------------------------------------------------
extern "C" void kernel_launch(void* const* d_in, const int* in_sizes, int n_in,
                              void* d_out, int out_size, void* d_ws, size_t ws_size,
                              hipStream_t stream) {
    (void)in_sizes; (void)n_in; (void)out_size; (void)ws_size;
    const float* I    = (const float*)d_in[0];
    const float* Q    = (const float*)d_in[1];
    const float* ew   = (const float*)d_in[2];
    const float* Wn1  = (const float*)d_in[3];
    const float* bn1  = (const float*)d_in[4];
    const float* Ws1  = (const float*)d_in[5];
    const float* bs1  = (const float*)d_in[6];
    const float* Wn2  = (const float*)d_in[7];
    const float* bn2  = (const float*)d_in[8];
    const float* Ws2  = (const float*)d_in[9];
    const float* bs2  = (const float*)d_in[10];
    const float* Wih0 = (const float*)d_in[11];
    const float* Whh0 = (const float*)d_in[12];
    const float* bih0 = (const float*)d_in[13];
    const float* bhh0 = (const float*)d_in[14];
    const float* Wih1 = (const float*)d_in[15];
    const float* Whh1 = (const float*)d_in[16];
    const float* bih1 = (const float*)d_in[17];
    const float* bhh1 = (const float*)d_in[18];
    const float* Wc1  = (const float*)d_in[19];
    const float* bc1  = (const float*)d_in[20];
    const float* Wc2  = (const float*)d_in[21];
    const float* bc2  = (const float*)d_in[22];
    float* out = (float*)d_out;

    // workspace (floats): ~90.4 MB
    float* wsp   = (float*)d_ws;
    float* adjn  = wsp;                           // 4096
    float* WihT0 = adjn  + 4096;                  // 32768
    float* WihT1 = WihT0 + 32768;                 // 65536
    short* adjfG  = (short*)(WihT1 + 65536);      // 3072 shorts
    short* wcatfG = adjfG + 3072;                 // 16384 shorts
    short* whhf0G = wcatfG + 16384;               // 131072 shorts
    short* whhf1G = whhf0G + 131072;              // 131072 shorts  (=> 140800 floats total)
    float* feats = WihT1 + 65536 + 140800;        // 2031616
    float* out0  = feats + 2031616;               // 4063232
    float* xg    = out0  + 4063232;               // 16252928 (shared by both layers)

    adj_kernel<<<1, 64, 0, stream>>>(ew, adjn);
    prep_kernel<<<522, 256, 0, stream>>>(Wih0, Whh0, Wih1, Whh1, adjn, Ws2, Wn2,
                                         WihT0, WihT1, adjfG, wcatfG, whhf0G, whhf1G);
    sage_mfma<<<512, 256, 0, stream>>>(I, Q, adjn, Wn1, bn1, Ws1, bs1,
                                       bn2, bs2, adjfG, wcatfG, feats);
    gemm512_kernel<64><<<dim3(496, 4), 256, 0, stream>>>(feats, WihT0, bih0, bhh0, xg);
    lstm_mfma<false><<<64, 512, 0, stream>>>(xg, whhf0G, out0,
                                             nullptr, nullptr, nullptr, nullptr, nullptr);
    gemm512_kernel<128><<<dim3(496, 4), 256, 0, stream>>>(out0, WihT1, bih1, bhh1, xg);
    lstm_mfma<true><<<64, 512, 0, stream>>>(xg, whhf1G, nullptr,
                                            Wc1, bc1, Wc2, bc2, out);
}